// Round 10
// baseline (652.855 us; speedup 1.0000x reference)
//
#include <hip/hip_runtime.h>

#define NN 100000
#define NE 1600000
#define NG 1000
#define ETOT (NE + NN)
#define NODES_PER_GRP 12500  // NN/8, XCD-affine binning for count/scatter

typedef _Float16 f16x8 __attribute__((ext_vector_type(8)));
typedef _Float16 f16x4 __attribute__((ext_vector_type(4)));
typedef _Float16 f16x2 __attribute__((ext_vector_type(2)));
typedef float f32x16 __attribute__((ext_vector_type(16)));
#define XROW 72  // xform LDS row stride (halves)

// ---------- h1 paired fp16 + fused att1 (one wave per node) ----------
__global__ void k_h1(const float* __restrict__ x, const float* __restrict__ ffw,
                     const float* __restrict__ ffb, const float* __restrict__ g1w,
                     const float* __restrict__ asw, const float* __restrict__ adw,
                     _Float16* __restrict__ h1p, float* __restrict__ asp,
                     float* __restrict__ ad_) {
    int tid = blockIdx.x * 256 + threadIdx.x;  // NN*64 exact
    int n = __builtin_amdgcn_readfirstlane(tid >> 6);
    int jp = threadIdx.x & 63;
    float xv[4];
#pragma unroll
    for (int k = 0; k < 4; k++) xv[k] = x[n * 4 + k];
    float h0[8];
#pragma unroll
    for (int o = 0; o < 8; o++) {
        float a = ffb[o];
#pragma unroll
        for (int k = 0; k < 4; k++) a = fmaf(xv[k], ffw[o * 4 + k], a);
        h0[o] = a;
    }
    const float* w0 = g1w + jp * 8;
    const float* w1 = g1w + (jp + 64) * 8;
    float a0 = 0.f, a1 = 0.f;
#pragma unroll
    for (int k = 0; k < 8; k++) { a0 = fmaf(h0[k], w0[k], a0); a1 = fmaf(h0[k], w1[k], a1); }
    f16x2 r; r[0] = (_Float16)a0; r[1] = (_Float16)a1;
    *(f16x2*)(h1p + ((size_t)n * 64 + jp) * 2) = r;
    float p0 = a0 * asw[jp], p1 = a1 * asw[jp + 64];
    float d0 = a0 * adw[jp], d1 = a1 * adw[jp + 64];
#pragma unroll
    for (int m = 1; m <= 16; m <<= 1) {
        p0 += __shfl_xor(p0, m, 64); p1 += __shfl_xor(p1, m, 64);
        d0 += __shfl_xor(d0, m, 64); d1 += __shfl_xor(d1, m, 64);
    }
    if ((jp & 31) == 0) {
        int half = jp >> 5;
        *(float2*)(asp + n * 4 + half * 2) = make_float2(p0, p1);
        ad_[n * 4 + half] = d0;
        ad_[n * 4 + 2 + half] = d1;
    }
}

// ---------- layer-2 attention coeffs ----------
__global__ void k_att2(const _Float16* __restrict__ h2h, const float* __restrict__ asw,
                       const float* __restrict__ adw, float* __restrict__ as_,
                       float* __restrict__ ad_) {
    int tid = blockIdx.x * 256 + threadIdx.x;
    if (tid >= NN * 4) return;
    int n = tid >> 2, h = tid & 3;
    const _Float16* hp = h2h + (size_t)n * 64 + h * 16;
    const float* ws_ = asw + h * 16;
    const float* wd_ = adw + h * 16;
    float a = 0.f, d = 0.f;
#pragma unroll
    for (int c = 0; c < 16; c++) {
        float hv = (float)hp[c];
        a = fmaf(hv, ws_[c], a); d = fmaf(hv, wd_[c], d);
    }
    as_[tid] = a; ad_[tid] = d;
}

// ---------- CSR build: XCD-affine binned count & scatter ----------
__global__ void k_count(const int* __restrict__ ei, int* __restrict__ deg) {
    int g = blockIdx.x & 7;
    int bi = blockIdx.x >> 3;
    int nb = gridDim.x >> 3;
    int lo = g * NODES_PER_GRP, hi = lo + NODES_PER_GRP;
    for (int e = bi * 256 + threadIdx.x; e < ETOT; e += nb * 256) {
        int dst = (e < NE) ? ei[NE + e] : (e - NE);
        if (dst >= lo && dst < hi) atomicAdd(&deg[dst], 1);
    }
}

__global__ void k_scan1(const int* __restrict__ deg, int* __restrict__ offs, int* __restrict__ bsum) {
    __shared__ int s[1024];
    int tid = threadIdx.x;
    int i = blockIdx.x * 1024 + tid;
    int v = (i < NN) ? deg[i] : 0;
    s[tid] = v;
    __syncthreads();
    for (int d = 1; d < 1024; d <<= 1) {
        int t = 0;
        if (tid >= d) t = s[tid - d];
        __syncthreads();
        if (tid >= d) s[tid] += t;
        __syncthreads();
    }
    if (i < NN) offs[i] = s[tid] - v;
    if (tid == 1023) bsum[blockIdx.x] = s[tid];
}

__global__ void k_scan2(int* __restrict__ bsum) {
    __shared__ int s[128];
    int tid = threadIdx.x;
    int v = (tid < 98) ? bsum[tid] : 0;
    s[tid] = v;
    __syncthreads();
    for (int d = 1; d < 128; d <<= 1) {
        int t = 0;
        if (tid >= d) t = s[tid - d];
        __syncthreads();
        if (tid >= d) s[tid] += t;
        __syncthreads();
    }
    bsum[tid] = s[tid] - v;
}

__global__ void k_scan3(int* __restrict__ offs, const int* __restrict__ bsum, int* __restrict__ cur) {
    int i = blockIdx.x * 1024 + threadIdx.x;
    if (i < NN) {
        int v = offs[i] + bsum[blockIdx.x];
        offs[i] = v; cur[i] = v;
    }
    if (i == 0) offs[NN] = ETOT;
}

__global__ void k_scatter(const int* __restrict__ ei, int* __restrict__ cur, int* __restrict__ srcs) {
    int g = blockIdx.x & 7;
    int bi = blockIdx.x >> 3;
    int nb = gridDim.x >> 3;
    int lo = g * NODES_PER_GRP, hi = lo + NODES_PER_GRP;
    for (int e = bi * 256 + threadIdx.x; e < ETOT; e += nb * 256) {
        int dst = (e < NE) ? ei[NE + e] : (e - NE);
        if (dst >= lo && dst < hi) {
            int src = (e < NE) ? ei[e] : dst;
            int p = atomicAdd(&cur[dst], 1);
            srcs[p] = src;
        }
    }
}

// ---------- GAT layer 1: scalarized single-pass softmax+aggregate ----------
__global__ void k_gat1(const int* __restrict__ offs, const int* __restrict__ srcs,
                       const float* __restrict__ asp, const float* __restrict__ ad_,
                       const _Float16* __restrict__ h1p, const float* __restrict__ bias,
                       _Float16* __restrict__ g1h) {
    int wid = __builtin_amdgcn_readfirstlane((blockIdx.x * 256 + threadIdx.x) >> 6);
    int lane = threadIdx.x & 63;
    if (wid >= NN) return;
    int off = offs[wid];
    int deg = offs[wid + 1] - off;
    int hA = lane >> 5;
    float4 adv = *(const float4*)(ad_ + wid * 4);
    float adA = hA ? adv.y : adv.x;
    float adB = hA ? adv.w : adv.z;
    float ws0 = 0.f, ws1 = 0.f, ac0 = 0.f, ac1 = 0.f;
    float ws0b = 0.f, ws1b = 0.f, ac0b = 0.f, ac1b = 0.f;
    for (int base = 0; base < deg; base += 64) {
        int idx = off + base + lane; if (idx >= ETOT) idx = ETOT - 1;
        int sv = srcs[idx];
        int cnt = deg - base; if (cnt > 64) cnt = 64;
        int j = 0;
        for (; j + 2 <= cnt; j += 2) {
            int sa = __builtin_amdgcn_readlane(sv, j);
            int sb = __builtin_amdgcn_readlane(sv, j + 1);
            float4 aa = *(const float4*)(asp + sa * 4);
            float4 ab = *(const float4*)(asp + sb * 4);
            f16x2 hpa = *(const f16x2*)(h1p + (size_t)sa * 128 + lane * 2);
            f16x2 hpb = *(const f16x2*)(h1p + (size_t)sb * 128 + lane * 2);
            float e0 = (hA ? aa.z : aa.x) + adA; e0 = fmaxf(e0, 0.2f * e0);
            float e1 = (hA ? aa.w : aa.y) + adB; e1 = fmaxf(e1, 0.2f * e1);
            float w0 = __expf(e0), w1 = __expf(e1);
            ws0 += w0; ws1 += w1;
            ac0 = fmaf(w0, (float)hpa[0], ac0); ac1 = fmaf(w1, (float)hpa[1], ac1);
            float e0b = (hA ? ab.z : ab.x) + adA; e0b = fmaxf(e0b, 0.2f * e0b);
            float e1b = (hA ? ab.w : ab.y) + adB; e1b = fmaxf(e1b, 0.2f * e1b);
            float w0b = __expf(e0b), w1b = __expf(e1b);
            ws0b += w0b; ws1b += w1b;
            ac0b = fmaf(w0b, (float)hpb[0], ac0b); ac1b = fmaf(w1b, (float)hpb[1], ac1b);
        }
        if (j < cnt) {
            int sa = __builtin_amdgcn_readlane(sv, j);
            float4 aa = *(const float4*)(asp + sa * 4);
            f16x2 hpa = *(const f16x2*)(h1p + (size_t)sa * 128 + lane * 2);
            float e0 = (hA ? aa.z : aa.x) + adA; e0 = fmaxf(e0, 0.2f * e0);
            float e1 = (hA ? aa.w : aa.y) + adB; e1 = fmaxf(e1, 0.2f * e1);
            float w0 = __expf(e0), w1 = __expf(e1);
            ws0 += w0; ws1 += w1;
            ac0 = fmaf(w0, (float)hpa[0], ac0); ac1 = fmaf(w1, (float)hpa[1], ac1);
        }
    }
    ws0 += ws0b; ws1 += ws1b; ac0 += ac0b; ac1 += ac1b;
    float v0 = ac0 / ws0 + bias[lane];      v0 = fmaxf(v0, 0.01f * v0);
    float v1 = ac1 / ws1 + bias[lane + 64]; v1 = fmaxf(v1, 0.01f * v1);
    g1h[(size_t)wid * 128 + lane] = (_Float16)v0;
    g1h[(size_t)wid * 128 + lane + 64] = (_Float16)v1;
}

// ---------- GAT layer 2: scalarized, fp16 output ----------
__global__ void k_gat2(const int* __restrict__ offs, const int* __restrict__ srcs,
                       const float* __restrict__ as_, const float* __restrict__ ad_,
                       const _Float16* __restrict__ h2h, const float* __restrict__ bias,
                       _Float16* __restrict__ g2h) {
    int wid = __builtin_amdgcn_readfirstlane((blockIdx.x * 256 + threadIdx.x) >> 6);
    int lane = threadIdx.x & 63;
    if (wid >= NN) return;
    int off = offs[wid];
    int deg = offs[wid + 1] - off;
    int hd = lane >> 4;
    float4 adv = *(const float4*)(ad_ + wid * 4);
    float t01 = (hd & 1) ? adv.y : adv.x;
    float t23 = (hd & 1) ? adv.w : adv.z;
    float adA = (hd & 2) ? t23 : t01;
    float ws = 0.f, ac = 0.f, wsb = 0.f, acb = 0.f;
    for (int base = 0; base < deg; base += 64) {
        int idx = off + base + lane; if (idx >= ETOT) idx = ETOT - 1;
        int sv = srcs[idx];
        int cnt = deg - base; if (cnt > 64) cnt = 64;
        int j = 0;
        for (; j + 2 <= cnt; j += 2) {
            int sa = __builtin_amdgcn_readlane(sv, j);
            int sb = __builtin_amdgcn_readlane(sv, j + 1);
            float4 av = *(const float4*)(as_ + sa * 4);
            float4 bv = *(const float4*)(as_ + sb * 4);
            float ha = (float)h2h[(size_t)sa * 64 + lane];
            float hb = (float)h2h[(size_t)sb * 64 + lane];
            float u01 = (hd & 1) ? av.y : av.x, u23 = (hd & 1) ? av.w : av.z;
            float ea = ((hd & 2) ? u23 : u01) + adA; ea = fmaxf(ea, 0.2f * ea);
            float v01 = (hd & 1) ? bv.y : bv.x, v23 = (hd & 1) ? bv.w : bv.z;
            float eb = ((hd & 2) ? v23 : v01) + adA; eb = fmaxf(eb, 0.2f * eb);
            float wa = __expf(ea), wb = __expf(eb);
            ws += wa; ac = fmaf(wa, ha, ac);
            wsb += wb; acb = fmaf(wb, hb, acb);
        }
        if (j < cnt) {
            int sa = __builtin_amdgcn_readlane(sv, j);
            float4 av = *(const float4*)(as_ + sa * 4);
            float u01 = (hd & 1) ? av.y : av.x, u23 = (hd & 1) ? av.w : av.z;
            float ea = ((hd & 2) ? u23 : u01) + adA; ea = fmaxf(ea, 0.2f * ea);
            float wa = __expf(ea);
            ws += wa; ac = fmaf(wa, (float)h2h[(size_t)sa * 64 + lane], ac);
        }
    }
    ws += wsb; ac += acb;
    float v = ac / ws + bias[lane]; v = fmaxf(v, 0.01f * v);
    g2h[(size_t)wid * 64 + lane] = (_Float16)v;
}

// ---------- h2[N,64] fp16 = g1h[N,128] @ gat2_w.T via MFMA, 1 wave = 32 nodes ----------
#define GROW 136
#define CROW 72
__global__ __launch_bounds__(256, 2) void k_h2m(const _Float16* __restrict__ g1h,
                                                const _Float16* __restrict__ apw2,
                                                _Float16* __restrict__ h2h) {
    __shared__ _Float16 ls[4 * 32 * GROW];
    const int t = threadIdx.x;
    const int w = t >> 6, l = t & 63;
    const int col = l & 31, hf = l >> 5;
    const int wv = blockIdx.x * 4 + w;
    const int nb = wv * 32;
    if (nb >= NN) return;
    _Float16* g16 = ls + w * (32 * GROW);
    const int r = l >> 1, hb = l & 1;
    {
        int nr = nb + r; if (nr >= NN) nr = NN - 1;
        const _Float16* src = g1h + (size_t)nr * 128 + hb * 64;
        _Float16* dst = g16 + r * GROW + hb * 64;
#pragma unroll
        for (int q = 0; q < 8; q++)
            *(f16x8*)(dst + q * 8) = *(const f16x8*)(src + q * 8);
    }
    f16x8 bf[8];
#pragma unroll
    for (int ks = 0; ks < 8; ks++)
        bf[ks] = *(const f16x8*)(g16 + col * GROW + ks * 16 + hf * 8);
    f32x16 acc0, acc1;
#pragma unroll
    for (int i = 0; i < 16; i++) { acc0[i] = 0.f; acc1[i] = 0.f; }
#pragma unroll
    for (int ks = 0; ks < 8; ks++) {
        f16x8 a0 = *(const f16x8*)(apw2 + ((0 * 8 + ks) * 64 + l) * 8);
        f16x8 a1 = *(const f16x8*)(apw2 + ((1 * 8 + ks) * 64 + l) * 8);
        acc0 = __builtin_amdgcn_mfma_f32_32x32x16_f16(a0, bf[ks], acc0, 0, 0, 0);
        acc1 = __builtin_amdgcn_mfma_f32_32x32x16_f16(a1, bf[ks], acc1, 0, 0, 0);
    }
    _Float16* c16 = g16;
#pragma unroll
    for (int rg = 0; rg < 4; rg++) {
        f16x4 h0, h1;
#pragma unroll
        for (int i = 0; i < 4; i++) { h0[i] = (_Float16)acc0[rg * 4 + i]; h1[i] = (_Float16)acc1[rg * 4 + i]; }
        *(f16x4*)(c16 + col * CROW + rg * 8 + hf * 4) = h0;
        *(f16x4*)(c16 + col * CROW + 32 + rg * 8 + hf * 4) = h1;
    }
    if (nb + r < NN) {
        _Float16* dst = h2h + (size_t)(nb + r) * 64 + hb * 32;
        const _Float16* srow = c16 + r * CROW + hb * 32;
#pragma unroll
        for (int q = 0; q < 4; q++)
            *(f16x8*)(dst + q * 8) = *(const f16x8*)(srow + q * 8);
    }
}

// ---------- fused attention: writes packed fp16 A-fragments directly + fused bias ----------
__global__ void k_fuse(const float* __restrict__ enc_in_w, const float* __restrict__ enc_in_b,
                       const float* __restrict__ enc_out_w, const float* __restrict__ enc_out_b,
                       const float* __restrict__ sa_in_w, const float* __restrict__ sa_in_b,
                       const float* __restrict__ sa_out_w, const float* __restrict__ sa_out_b,
                       const float* __restrict__ ca_in_w, const float* __restrict__ ca_in_b,
                       const float* __restrict__ ca_out_w, const float* __restrict__ ca_out_b,
                       _Float16* __restrict__ apk, float* __restrict__ fb) {
    int tid = blockIdx.x * 256 + threadIdx.x;  // 6*64*64 = 24576 exact
    int p = tid >> 12, r = tid & 4095, j = r >> 6, k = r & 63;
    int li = p & 1;
    const float *iw, *ib, *ow, *ob;
    if (p < 2)      { iw = enc_in_w + li * 12288; ib = enc_in_b + li * 192; ow = enc_out_w + li * 4096; ob = enc_out_b + li * 64; }
    else if (p < 4) { iw = sa_in_w + li * 12288;  ib = sa_in_b + li * 192;  ow = sa_out_w + li * 4096;  ob = sa_out_b + li * 64; }
    else            { iw = ca_in_w + li * 12288;  ib = ca_in_b + li * 192;  ow = ca_out_w + li * 4096;  ob = ca_out_b + li * 64; }
    float a = 0.f;
    for (int m = 0; m < 64; m++) a = fmaf(ow[j * 64 + m], iw[(128 + m) * 64 + k], a);
    // packed A-frag position for (m=j, k): mt=j>>5, ks=k>>4, l=(k>>3&1)*32+(j&31), d=k&7
    int l = ((k >> 3) & 1) * 32 + (j & 31);
    apk[p * 4096 + (((j >> 5) * 4 + (k >> 4)) * 64 + l) * 8 + (k & 7)] = (_Float16)a;
    if (k == 0) {
        float fa = ob[j];
        for (int m = 0; m < 64; m++) fa = fmaf(ow[j * 64 + m], ib[128 + m], fa);
        fb[p * 64 + j] = fa;
    }
}

// ---------- pack FFN weights (direct from inputs) + gat2_w A-fragments ----------
#define APK_F1 24576
#define APK_F2 90112
#define APK_TOT 155648
__global__ void k_apack(const float* __restrict__ ef1, const float* __restrict__ df1,
                        const float* __restrict__ ef2, const float* __restrict__ df2,
                        const float* __restrict__ g2w, _Float16* __restrict__ apk,
                        _Float16* __restrict__ apw2) {
    int tid = blockIdx.x * 256 + threadIdx.x;  // 544*256 = 139264 exact
    if (tid < 65536) {  // F1: f1t[pl][k*256+i] = f1[i*64+k] composed -> direct f1[m*64+k]
        int pl = tid >> 14, idx = tid & 16383;
        int mt = idx >> 11, ks = (idx >> 9) & 3, l = (idx >> 3) & 63, d = idx & 7;
        int m = mt * 32 + (l & 31), k = ks * 16 + (l >> 5) * 8 + d;
        const float* f1 = (pl < 2) ? ef1 + pl * 16384 : df1 + (pl - 2) * 16384;
        apk[APK_F1 + pl * 16384 + idx] = (_Float16)f1[m * 64 + k];
    } else if (tid < 131072) {  // F2: f2t composed -> direct f2[m*256+k]
        int r = tid - 65536;
        int pl = r >> 14, idx = r & 16383;
        int mt = idx >> 13, ks = (idx >> 9) & 15, l = (idx >> 3) & 63, d = idx & 7;
        int m = mt * 32 + (l & 31), k = ks * 16 + (l >> 5) * 8 + d;
        const float* f2 = (pl < 2) ? ef2 + pl * 16384 : df2 + (pl - 2) * 16384;
        apk[APK_F2 + pl * 16384 + idx] = (_Float16)f2[m * 256 + k];
    } else {  // gat2_w
        int r = tid - 131072;
        int mtks = r >> 9, l = (r >> 3) & 63, d = r & 7;
        int mt = mtks >> 3, ks = mtks & 7;
        int m = mt * 32 + (l & 31), k = ks * 16 + (l >> 5) * 8 + d;
        apw2[r] = (_Float16)g2w[m * 128 + k];
    }
}

// ---------- MFMA transformer: 1 wave = 32 nodes, no barriers ----------
struct XQ {
    const _Float16* apk; const float* fb;
    const float* ef1b; const float* ef2b; const float* df1b; const float* df2b;
    const float* el1g; const float* el1b; const float* el2g; const float* el2b;
    const float* dl1g; const float* dl1b; const float* dl2g; const float* dl2b;
    const float* dl3g; const float* dl3b;
};

__device__ __forceinline__ void xstore32(_Float16* xw, const float y[2][16], int col, int hf) {
#pragma unroll
    for (int mt = 0; mt < 2; mt++)
#pragma unroll
        for (int rg = 0; rg < 4; rg++) {
            f16x4 h4;
#pragma unroll
            for (int i = 0; i < 4; i++) h4[i] = (_Float16)y[mt][rg * 4 + i];
            *(f16x4*)(xw + col * XROW + mt * 32 + rg * 8 + hf * 4) = h4;
        }
}

__device__ __forceinline__ void loadbf32(const _Float16* xw, f16x8 bf[4], int col, int hf) {
#pragma unroll
    for (int ks = 0; ks < 4; ks++)
        bf[ks] = *(const f16x8*)(xw + col * XROW + ks * 16 + hf * 8);
}

__device__ __forceinline__ void lnw32(float y[2][16], const float* g, const float* b, int hf) {
    float s = 0.f, q = 0.f;
#pragma unroll
    for (int mt = 0; mt < 2; mt++)
#pragma unroll
        for (int r = 0; r < 16; r++) { float v = y[mt][r]; s += v; q = fmaf(v, v, q); }
    s += __shfl_xor(s, 32, 64);
    q += __shfl_xor(q, 32, 64);
    float m = s * 0.015625f;
    float var = fmaf(q, 0.015625f, -m * m);
    float rs = rsqrtf(var + 1e-5f);
#pragma unroll
    for (int mt = 0; mt < 2; mt++)
#pragma unroll
        for (int rg = 0; rg < 4; rg++) {
            float4 g4 = *(const float4*)(g + mt * 32 + rg * 8 + hf * 4);
            float4 b4 = *(const float4*)(b + mt * 32 + rg * 8 + hf * 4);
            float* yp = &y[mt][rg * 4];
            yp[0] = fmaf((yp[0] - m) * rs, g4.x, b4.x);
            yp[1] = fmaf((yp[1] - m) * rs, g4.y, b4.y);
            yp[2] = fmaf((yp[2] - m) * rs, g4.z, b4.z);
            yp[3] = fmaf((yp[3] - m) * rs, g4.w, b4.w);
        }
}

__global__ __launch_bounds__(256, 4) void k_xform(const _Float16* __restrict__ yin,
                                                  float* __restrict__ yout, XQ P) {
    __shared__ _Float16 xs[4 * 32 * XROW];
    const int t = threadIdx.x;
    const int w = t >> 6, l = t & 63;
    const int col = l & 31, hf = l >> 5;
    _Float16* xw = xs + w * (32 * XROW);
    const int node = (blockIdx.x * 4 + w) * 32 + col;
    const int nc = node < NN ? node : NN - 1;

    float y[2][16];
#pragma unroll
    for (int mt = 0; mt < 2; mt++) {
        const _Float16* src = yin + (size_t)nc * 64 + mt * 32 + hf * 4;
#pragma unroll
        for (int rg = 0; rg < 4; rg++) {
            f16x4 v = *(const f16x4*)(src + rg * 8);
#pragma unroll
            for (int i = 0; i < 4; i++) y[mt][rg * 4 + i] = (float)v[i];
        }
    }
    f16x8 bf[4];
    xstore32(xw, y, col, hf);
    loadbf32(xw, bf, col, hf);

#pragma unroll 1
    for (int layer = 0; layer < 4; layer++) {
        const bool enc = layer < 2;
        const int li = enc ? layer : layer - 2;
        const int nat = enc ? 1 : 2;
#pragma unroll 1
        for (int at = 0; at < nat; at++) {
            const int p = enc ? layer : (at == 0 ? 2 + li : 4 + li);
            const _Float16* apA = P.apk + p * 4096;
            const float* fbp = P.fb + p * 64;
            f32x16 acc[2];
#pragma unroll
            for (int mt = 0; mt < 2; mt++) {
#pragma unroll
                for (int rg = 0; rg < 4; rg++) {
                    float4 b4 = *(const float4*)(fbp + mt * 32 + rg * 8 + hf * 4);
                    acc[mt][rg * 4 + 0] = b4.x; acc[mt][rg * 4 + 1] = b4.y;
                    acc[mt][rg * 4 + 2] = b4.z; acc[mt][rg * 4 + 3] = b4.w;
                }
            }
#pragma unroll
            for (int mt = 0; mt < 2; mt++)
#pragma unroll
                for (int ks = 0; ks < 4; ks++) {
                    f16x8 af = *(const f16x8*)(apA + ((mt * 4 + ks) * 64 + l) * 8);
                    acc[mt] = __builtin_amdgcn_mfma_f32_32x32x16_f16(af, bf[ks], acc[mt], 0, 0, 0);
                }
#pragma unroll
            for (int mt = 0; mt < 2; mt++)
#pragma unroll
                for (int r = 0; r < 16; r++) y[mt][r] += acc[mt][r];
            const float *g, *b;
            if (enc)          { g = P.el1g + li * 64; b = P.el1b + li * 64; }
            else if (at == 0) { g = P.dl1g + li * 64; b = P.dl1b + li * 64; }
            else              { g = P.dl2g + li * 64; b = P.dl2b + li * 64; }
            lnw32(y, g, b, hf);
            xstore32(xw, y, col, hf);
            loadbf32(xw, bf, col, hf);
        }
        const int pl = enc ? layer : 2 + li;
        const _Float16* apF1 = P.apk + APK_F1 + pl * 16384;
        const _Float16* apF2 = P.apk + APK_F2 + pl * 16384;
        const float* f1bp = (enc ? P.ef1b : P.df1b) + li * 256;
        const float* f2bp = (enc ? P.ef2b : P.df2b) + li * 64;
        f32x16 out[2];
#pragma unroll
        for (int mt = 0; mt < 2; mt++) {
#pragma unroll
            for (int rg = 0; rg < 4; rg++) {
                float4 b4 = *(const float4*)(f2bp + mt * 32 + rg * 8 + hf * 4);
                out[mt][rg * 4 + 0] = b4.x; out[mt][rg * 4 + 1] = b4.y;
                out[mt][rg * 4 + 2] = b4.z; out[mt][rg * 4 + 3] = b4.w;
            }
        }
#pragma unroll 1
        for (int c = 0; c < 4; c++) {
            f32x16 ha[2];
#pragma unroll
            for (int hmt = 0; hmt < 2; hmt++) {
#pragma unroll
                for (int rg = 0; rg < 4; rg++) {
                    float4 b4 = *(const float4*)(f1bp + c * 64 + hmt * 32 + rg * 8 + hf * 4);
                    ha[hmt][rg * 4 + 0] = b4.x; ha[hmt][rg * 4 + 1] = b4.y;
                    ha[hmt][rg * 4 + 2] = b4.z; ha[hmt][rg * 4 + 3] = b4.w;
                }
            }
#pragma unroll
            for (int hmt = 0; hmt < 2; hmt++)
#pragma unroll
                for (int ks = 0; ks < 4; ks++) {
                    f16x8 af = *(const f16x8*)(apF1 + (((2 * c + hmt) * 4 + ks) * 64 + l) * 8);
                    ha[hmt] = __builtin_amdgcn_mfma_f32_32x32x16_f16(af, bf[ks], ha[hmt], 0, 0, 0);
                }
            // ReLU + transpose chunk through LDS (bf regs keep y)
#pragma unroll
            for (int hmt = 0; hmt < 2; hmt++)
#pragma unroll
                for (int rg = 0; rg < 4; rg++) {
                    f16x4 h4;
#pragma unroll
                    for (int i = 0; i < 4; i++)
                        h4[i] = (_Float16)fmaxf(ha[hmt][rg * 4 + i], 0.f);
                    *(f16x4*)(xw + col * XROW + hmt * 32 + rg * 8 + hf * 4) = h4;
                }
#pragma unroll
            for (int ksl = 0; ksl < 4; ksl++) {
                f16x8 hbf = *(const f16x8*)(xw + col * XROW + ksl * 16 + hf * 8);
#pragma unroll
                for (int mt = 0; mt < 2; mt++) {
                    f16x8 af = *(const f16x8*)(apF2 + ((mt * 16 + c * 4 + ksl) * 64 + l) * 8);
                    out[mt] = __builtin_amdgcn_mfma_f32_32x32x16_f16(af, hbf, out[mt], 0, 0, 0);
                }
            }
        }
#pragma unroll
        for (int mt = 0; mt < 2; mt++)
#pragma unroll
            for (int r = 0; r < 16; r++) y[mt][r] += out[mt][r];
        const float* g2 = (enc ? P.el2g : P.dl3g) + li * 64;
        const float* b2 = (enc ? P.el2b : P.dl3b) + li * 64;
        lnw32(y, g2, b2, hf);
        if (layer < 3) {
            xstore32(xw, y, col, hf);
            loadbf32(xw, bf, col, hf);
        }
    }
    if (node < NN) {
#pragma unroll
        for (int mt = 0; mt < 2; mt++) {
            float* dst = yout + (size_t)node * 64 + mt * 32 + hf * 4;
#pragma unroll
            for (int rg = 0; rg < 4; rg++) {
                const float* yp = &y[mt][rg * 4];
                *(float4*)(dst + rg * 8) = make_float4(yp[0], yp[1], yp[2], yp[3]);
            }
        }
    }
}

// ---------- global mean pool ----------
__global__ void k_pool(const float* __restrict__ y, const int* __restrict__ batch,
                       float* __restrict__ pooled) {
    int b = blockIdx.x;
    int t = threadIdx.x;
    int ch = t & 63, r = t >> 6;
    int lo = 0, hi = NN;
    while (lo < hi) { int mid = (lo + hi) >> 1; if (batch[mid] < b) lo = mid + 1; else hi = mid; }
    int st = lo;
    hi = NN;
    while (lo < hi) { int mid = (lo + hi) >> 1; if (batch[mid] < b + 1) lo = mid + 1; else hi = mid; }
    int en = lo;
    float s = 0.f;
    for (int i = st + r; i < en; i += 4) s += y[(size_t)i * 64 + ch];
    __shared__ float red[256];
    red[t] = s;
    __syncthreads();
    if (t < 64) {
        float tot = red[t] + red[t + 64] + red[t + 128] + red[t + 192];
        int cnt = en - st; if (cnt < 1) cnt = 1;
        pooled[b * 64 + t] = tot / (float)cnt;
    }
}

// ---------- final fc ----------
__global__ void k_fc(const float* __restrict__ pooled, const float* __restrict__ fcw,
                     const float* __restrict__ fcb, float* __restrict__ out) {
    int tid = blockIdx.x * 256 + threadIdx.x;
    if (tid >= NG * 33) return;
    int g = tid / 33, o = tid - g * 33;
    const float* p = pooled + g * 64;
    const float* w = fcw + o * 64;
    float a0 = 0.f, a1 = 0.f, a2 = 0.f, a3 = 0.f;
#pragma unroll
    for (int k = 0; k < 16; k++) {
        a0 = fmaf(p[4 * k], w[4 * k], a0);
        a1 = fmaf(p[4 * k + 1], w[4 * k + 1], a1);
        a2 = fmaf(p[4 * k + 2], w[4 * k + 2], a2);
        a3 = fmaf(p[4 * k + 3], w[4 * k + 3], a3);
    }
    out[tid] = fcb[o] + (a0 + a1) + (a2 + a3);
}

extern "C" void kernel_launch(void* const* d_in, const int* in_sizes, int n_in,
                              void* d_out, int out_size, void* d_ws, size_t ws_size,
                              hipStream_t stream) {
    (void)in_sizes; (void)n_in; (void)out_size; (void)ws_size;
    char* ws = (char*)d_ws;
    size_t o = 0;
    auto A = [&](size_t b) { size_t r = o; o += (b + 255) & ~(size_t)255; return r; };
    _Float16* h1p = (_Float16*)(ws + A((size_t)NN * 128 * 2));
    _Float16* h2h = (_Float16*)(ws + A((size_t)NN * 64 * 2));
    _Float16* g1h = (_Float16*)(ws + A((size_t)NN * 128 * 2));
    _Float16* g2h = (_Float16*)(ws + A((size_t)NN * 64 * 2));
    float* f_y   = (float*)(ws + A((size_t)NN * 64 * 4));
    float* f_asp = (float*)(ws + A((size_t)NN * 4 * 4));
    float* f_ad1 = (float*)(ws + A((size_t)NN * 4 * 4));
    float* f_as2 = (float*)(ws + A((size_t)NN * 4 * 4));
    float* f_ad2 = (float*)(ws + A((size_t)NN * 4 * 4));
    int* i_off   = (int*)(ws + A((size_t)(NN + 1) * 4));
    int* i_cur   = (int*)(ws + A((size_t)NN * 4));
    int* i_deg   = (int*)(ws + A((size_t)NN * 4));
    int* i_bsum  = (int*)(ws + A((size_t)1024 * 4));
    int* i_srcs  = (int*)(ws + A((size_t)ETOT * 4));
    float* f_fb  = (float*)(ws + A((size_t)6 * 64 * 4));
    _Float16* f_apk = (_Float16*)(ws + A((size_t)APK_TOT * 2));
    _Float16* apw2  = (_Float16*)(ws + A((size_t)8192 * 2));
    float* f_pool= (float*)(ws + A((size_t)NG * 64 * 4));

    const float* x   = (const float*)d_in[0];
    const int* ei    = (const int*)d_in[1];
    const int* batch = (const int*)d_in[2];
    #define F32(i) ((const float*)d_in[i])

    hipMemsetAsync(i_deg, 0, (size_t)NN * 4, stream);
    k_h1<<<NN * 64 / 256, 256, 0, stream>>>(x, F32(3), F32(4), F32(5), F32(6), F32(7),
                                            h1p, f_asp, f_ad1);
    k_count<<<8 * 128, 256, 0, stream>>>(ei, i_deg);
    k_scan1<<<98, 1024, 0, stream>>>(i_deg, i_off, i_bsum);
    k_scan2<<<1, 128, 0, stream>>>(i_bsum);
    k_scan3<<<98, 1024, 0, stream>>>(i_off, i_bsum, i_cur);
    k_scatter<<<8 * 128, 256, 0, stream>>>(ei, i_cur, i_srcs);
    k_gat1<<<NN * 64 / 256, 256, 0, stream>>>(i_off, i_srcs, f_asp, f_ad1, h1p, F32(8), g1h);
    k_apack<<<544, 256, 0, stream>>>(F32(17), F32(33), F32(19), F32(35), F32(9), f_apk, apw2);
    k_h2m<<<(NN / 32 + 3) / 4, 256, 0, stream>>>(g1h, apw2, h2h);
    k_att2<<<(NN * 4 + 255) / 256, 256, 0, stream>>>(h2h, F32(10), F32(11), f_as2, f_ad2);
    k_gat2<<<NN * 64 / 256, 256, 0, stream>>>(i_off, i_srcs, f_as2, f_ad2, h2h, F32(12), g2h);
    k_fuse<<<24576 / 256, 256, 0, stream>>>(F32(13), F32(14), F32(15), F32(16),
                                            F32(25), F32(26), F32(27), F32(28),
                                            F32(29), F32(30), F32(31), F32(32),
                                            f_apk, f_fb);
    XQ Q;
    Q.apk = f_apk; Q.fb = f_fb;
    Q.ef1b = F32(18); Q.ef2b = F32(20);
    Q.df1b = F32(34); Q.df2b = F32(36);
    Q.el1g = F32(21); Q.el1b = F32(22); Q.el2g = F32(23); Q.el2b = F32(24);
    Q.dl1g = F32(37); Q.dl1b = F32(38); Q.dl2g = F32(39); Q.dl2b = F32(40);
    Q.dl3g = F32(41); Q.dl3b = F32(42);
    k_xform<<<(NN + 127) / 128, 256, 0, stream>>>(g2h, f_y, Q);
    k_pool<<<NG, 256, 0, stream>>>(f_y, batch, f_pool);
    k_fc<<<(NG * 33 + 255) / 256, 256, 0, stream>>>(f_pool, F32(43), F32(44), (float*)d_out);
    #undef F32
}

// Round 11
// 605.319 us; speedup vs baseline: 1.0785x; 1.0785x over previous
//
#include <hip/hip_runtime.h>

#define NN 100000
#define NE 1600000
#define NG 1000
#define ETOT (NE + NN)
#define NODES_PER_GRP 12500  // NN/8, XCD-affine binning for count/scatter

typedef _Float16 f16x8 __attribute__((ext_vector_type(8)));
typedef _Float16 f16x4 __attribute__((ext_vector_type(4)));
typedef _Float16 f16x2 __attribute__((ext_vector_type(2)));
typedef float f32x16 __attribute__((ext_vector_type(16)));
#define XROW 72  // xform LDS row stride (halves)

// ---------- h1 paired fp16 + fused att1 (one wave per node) ----------
__global__ void k_h1(const float* __restrict__ x, const float* __restrict__ ffw,
                     const float* __restrict__ ffb, const float* __restrict__ g1w,
                     const float* __restrict__ asw, const float* __restrict__ adw,
                     _Float16* __restrict__ h1p, float* __restrict__ asp,
                     float* __restrict__ ad_) {
    int tid = blockIdx.x * 256 + threadIdx.x;  // NN*64 exact
    int n = __builtin_amdgcn_readfirstlane(tid >> 6);
    int jp = threadIdx.x & 63;
    float xv[4];
#pragma unroll
    for (int k = 0; k < 4; k++) xv[k] = x[n * 4 + k];
    float h0[8];
#pragma unroll
    for (int o = 0; o < 8; o++) {
        float a = ffb[o];
#pragma unroll
        for (int k = 0; k < 4; k++) a = fmaf(xv[k], ffw[o * 4 + k], a);
        h0[o] = a;
    }
    const float* w0 = g1w + jp * 8;
    const float* w1 = g1w + (jp + 64) * 8;
    float a0 = 0.f, a1 = 0.f;
#pragma unroll
    for (int k = 0; k < 8; k++) { a0 = fmaf(h0[k], w0[k], a0); a1 = fmaf(h0[k], w1[k], a1); }
    f16x2 r; r[0] = (_Float16)a0; r[1] = (_Float16)a1;
    *(f16x2*)(h1p + ((size_t)n * 64 + jp) * 2) = r;
    float p0 = a0 * asw[jp], p1 = a1 * asw[jp + 64];
    float d0 = a0 * adw[jp], d1 = a1 * adw[jp + 64];
#pragma unroll
    for (int m = 1; m <= 16; m <<= 1) {
        p0 += __shfl_xor(p0, m, 64); p1 += __shfl_xor(p1, m, 64);
        d0 += __shfl_xor(d0, m, 64); d1 += __shfl_xor(d1, m, 64);
    }
    if ((jp & 31) == 0) {
        int half = jp >> 5;
        *(float2*)(asp + n * 4 + half * 2) = make_float2(p0, p1);
        ad_[n * 4 + half] = d0;
        ad_[n * 4 + 2 + half] = d1;
    }
}

// ---------- layer-2 attention coeffs ----------
__global__ void k_att2(const _Float16* __restrict__ h2h, const float* __restrict__ asw,
                       const float* __restrict__ adw, float* __restrict__ as_,
                       float* __restrict__ ad_) {
    int tid = blockIdx.x * 256 + threadIdx.x;
    if (tid >= NN * 4) return;
    int n = tid >> 2, h = tid & 3;
    const _Float16* hp = h2h + (size_t)n * 64 + h * 16;
    const float* ws_ = asw + h * 16;
    const float* wd_ = adw + h * 16;
    float a = 0.f, d = 0.f;
#pragma unroll
    for (int c = 0; c < 16; c++) {
        float hv = (float)hp[c];
        a = fmaf(hv, ws_[c], a); d = fmaf(hv, wd_[c], d);
    }
    as_[tid] = a; ad_[tid] = d;
}

// ---------- CSR build: XCD-affine binned count & scatter ----------
__global__ void k_count(const int* __restrict__ ei, int* __restrict__ deg) {
    int g = blockIdx.x & 7;
    int bi = blockIdx.x >> 3;
    int nb = gridDim.x >> 3;
    int lo = g * NODES_PER_GRP, hi = lo + NODES_PER_GRP;
    for (int e = bi * 256 + threadIdx.x; e < ETOT; e += nb * 256) {
        int dst = (e < NE) ? ei[NE + e] : (e - NE);
        if (dst >= lo && dst < hi) atomicAdd(&deg[dst], 1);
    }
}

__global__ void k_scan1(const int* __restrict__ deg, int* __restrict__ offs, int* __restrict__ bsum) {
    __shared__ int s[1024];
    int tid = threadIdx.x;
    int i = blockIdx.x * 1024 + tid;
    int v = (i < NN) ? deg[i] : 0;
    s[tid] = v;
    __syncthreads();
    for (int d = 1; d < 1024; d <<= 1) {
        int t = 0;
        if (tid >= d) t = s[tid - d];
        __syncthreads();
        if (tid >= d) s[tid] += t;
        __syncthreads();
    }
    if (i < NN) offs[i] = s[tid] - v;
    if (tid == 1023) bsum[blockIdx.x] = s[tid];
}

__global__ void k_scan2(int* __restrict__ bsum) {
    __shared__ int s[128];
    int tid = threadIdx.x;
    int v = (tid < 98) ? bsum[tid] : 0;
    s[tid] = v;
    __syncthreads();
    for (int d = 1; d < 128; d <<= 1) {
        int t = 0;
        if (tid >= d) t = s[tid - d];
        __syncthreads();
        if (tid >= d) s[tid] += t;
        __syncthreads();
    }
    bsum[tid] = s[tid] - v;
}

__global__ void k_scan3(int* __restrict__ offs, const int* __restrict__ bsum, int* __restrict__ cur) {
    int i = blockIdx.x * 1024 + threadIdx.x;
    if (i < NN) {
        int v = offs[i] + bsum[blockIdx.x];
        offs[i] = v; cur[i] = v;
    }
    if (i == 0) offs[NN] = ETOT;
}

__global__ void k_scatter(const int* __restrict__ ei, int* __restrict__ cur, int* __restrict__ srcs) {
    int g = blockIdx.x & 7;
    int bi = blockIdx.x >> 3;
    int nb = gridDim.x >> 3;
    int lo = g * NODES_PER_GRP, hi = lo + NODES_PER_GRP;
    for (int e = bi * 256 + threadIdx.x; e < ETOT; e += nb * 256) {
        int dst = (e < NE) ? ei[NE + e] : (e - NE);
        if (dst >= lo && dst < hi) {
            int src = (e < NE) ? ei[e] : dst;
            int p = atomicAdd(&cur[dst], 1);
            srcs[p] = src;
        }
    }
}

// ---------- GAT layer 1: scalarized single-pass softmax+aggregate ----------
__global__ void k_gat1(const int* __restrict__ offs, const int* __restrict__ srcs,
                       const float* __restrict__ asp, const float* __restrict__ ad_,
                       const _Float16* __restrict__ h1p, const float* __restrict__ bias,
                       _Float16* __restrict__ g1h) {
    int wid = __builtin_amdgcn_readfirstlane((blockIdx.x * 256 + threadIdx.x) >> 6);
    int lane = threadIdx.x & 63;
    if (wid >= NN) return;
    int off = offs[wid];
    int deg = offs[wid + 1] - off;
    int hA = lane >> 5;
    float4 adv = *(const float4*)(ad_ + wid * 4);
    float adA = hA ? adv.y : adv.x;
    float adB = hA ? adv.w : adv.z;
    float ws0 = 0.f, ws1 = 0.f, ac0 = 0.f, ac1 = 0.f;
    float ws0b = 0.f, ws1b = 0.f, ac0b = 0.f, ac1b = 0.f;
    for (int base = 0; base < deg; base += 64) {
        int idx = off + base + lane; if (idx >= ETOT) idx = ETOT - 1;
        int sv = srcs[idx];
        int cnt = deg - base; if (cnt > 64) cnt = 64;
        int j = 0;
        for (; j + 2 <= cnt; j += 2) {
            int sa = __builtin_amdgcn_readlane(sv, j);
            int sb = __builtin_amdgcn_readlane(sv, j + 1);
            float4 aa = *(const float4*)(asp + sa * 4);
            float4 ab = *(const float4*)(asp + sb * 4);
            f16x2 hpa = *(const f16x2*)(h1p + (size_t)sa * 128 + lane * 2);
            f16x2 hpb = *(const f16x2*)(h1p + (size_t)sb * 128 + lane * 2);
            float e0 = (hA ? aa.z : aa.x) + adA; e0 = fmaxf(e0, 0.2f * e0);
            float e1 = (hA ? aa.w : aa.y) + adB; e1 = fmaxf(e1, 0.2f * e1);
            float w0 = __expf(e0), w1 = __expf(e1);
            ws0 += w0; ws1 += w1;
            ac0 = fmaf(w0, (float)hpa[0], ac0); ac1 = fmaf(w1, (float)hpa[1], ac1);
            float e0b = (hA ? ab.z : ab.x) + adA; e0b = fmaxf(e0b, 0.2f * e0b);
            float e1b = (hA ? ab.w : ab.y) + adB; e1b = fmaxf(e1b, 0.2f * e1b);
            float w0b = __expf(e0b), w1b = __expf(e1b);
            ws0b += w0b; ws1b += w1b;
            ac0b = fmaf(w0b, (float)hpb[0], ac0b); ac1b = fmaf(w1b, (float)hpb[1], ac1b);
        }
        if (j < cnt) {
            int sa = __builtin_amdgcn_readlane(sv, j);
            float4 aa = *(const float4*)(asp + sa * 4);
            f16x2 hpa = *(const f16x2*)(h1p + (size_t)sa * 128 + lane * 2);
            float e0 = (hA ? aa.z : aa.x) + adA; e0 = fmaxf(e0, 0.2f * e0);
            float e1 = (hA ? aa.w : aa.y) + adB; e1 = fmaxf(e1, 0.2f * e1);
            float w0 = __expf(e0), w1 = __expf(e1);
            ws0 += w0; ws1 += w1;
            ac0 = fmaf(w0, (float)hpa[0], ac0); ac1 = fmaf(w1, (float)hpa[1], ac1);
        }
    }
    ws0 += ws0b; ws1 += ws1b; ac0 += ac0b; ac1 += ac1b;
    float v0 = ac0 / ws0 + bias[lane];      v0 = fmaxf(v0, 0.01f * v0);
    float v1 = ac1 / ws1 + bias[lane + 64]; v1 = fmaxf(v1, 0.01f * v1);
    g1h[(size_t)wid * 128 + lane] = (_Float16)v0;
    g1h[(size_t)wid * 128 + lane + 64] = (_Float16)v1;
}

// ---------- GAT layer 2: scalarized, fp16 output ----------
__global__ void k_gat2(const int* __restrict__ offs, const int* __restrict__ srcs,
                       const float* __restrict__ as_, const float* __restrict__ ad_,
                       const _Float16* __restrict__ h2h, const float* __restrict__ bias,
                       _Float16* __restrict__ g2h) {
    int wid = __builtin_amdgcn_readfirstlane((blockIdx.x * 256 + threadIdx.x) >> 6);
    int lane = threadIdx.x & 63;
    if (wid >= NN) return;
    int off = offs[wid];
    int deg = offs[wid + 1] - off;
    int hd = lane >> 4;
    float4 adv = *(const float4*)(ad_ + wid * 4);
    float t01 = (hd & 1) ? adv.y : adv.x;
    float t23 = (hd & 1) ? adv.w : adv.z;
    float adA = (hd & 2) ? t23 : t01;
    float ws = 0.f, ac = 0.f, wsb = 0.f, acb = 0.f;
    for (int base = 0; base < deg; base += 64) {
        int idx = off + base + lane; if (idx >= ETOT) idx = ETOT - 1;
        int sv = srcs[idx];
        int cnt = deg - base; if (cnt > 64) cnt = 64;
        int j = 0;
        for (; j + 2 <= cnt; j += 2) {
            int sa = __builtin_amdgcn_readlane(sv, j);
            int sb = __builtin_amdgcn_readlane(sv, j + 1);
            float4 av = *(const float4*)(as_ + sa * 4);
            float4 bv = *(const float4*)(as_ + sb * 4);
            float ha = (float)h2h[(size_t)sa * 64 + lane];
            float hb = (float)h2h[(size_t)sb * 64 + lane];
            float u01 = (hd & 1) ? av.y : av.x, u23 = (hd & 1) ? av.w : av.z;
            float ea = ((hd & 2) ? u23 : u01) + adA; ea = fmaxf(ea, 0.2f * ea);
            float v01 = (hd & 1) ? bv.y : bv.x, v23 = (hd & 1) ? bv.w : bv.z;
            float eb = ((hd & 2) ? v23 : v01) + adA; eb = fmaxf(eb, 0.2f * eb);
            float wa = __expf(ea), wb = __expf(eb);
            ws += wa; ac = fmaf(wa, ha, ac);
            wsb += wb; acb = fmaf(wb, hb, acb);
        }
        if (j < cnt) {
            int sa = __builtin_amdgcn_readlane(sv, j);
            float4 av = *(const float4*)(as_ + sa * 4);
            float u01 = (hd & 1) ? av.y : av.x, u23 = (hd & 1) ? av.w : av.z;
            float ea = ((hd & 2) ? u23 : u01) + adA; ea = fmaxf(ea, 0.2f * ea);
            float wa = __expf(ea);
            ws += wa; ac = fmaf(wa, (float)h2h[(size_t)sa * 64 + lane], ac);
        }
    }
    ws += wsb; ac += acb;
    float v = ac / ws + bias[lane]; v = fmaxf(v, 0.01f * v);
    g2h[(size_t)wid * 64 + lane] = (_Float16)v;
}

// ---------- h2[N,64] fp16 = g1h[N,128] @ gat2_w.T via MFMA, 1 wave = 32 nodes ----------
#define GROW 136
#define CROW 72
__global__ __launch_bounds__(256, 2) void k_h2m(const _Float16* __restrict__ g1h,
                                                const _Float16* __restrict__ apw2,
                                                _Float16* __restrict__ h2h) {
    __shared__ _Float16 ls[4 * 32 * GROW];
    const int t = threadIdx.x;
    const int w = t >> 6, l = t & 63;
    const int col = l & 31, hf = l >> 5;
    const int wv = blockIdx.x * 4 + w;
    const int nb = wv * 32;
    if (nb >= NN) return;
    _Float16* g16 = ls + w * (32 * GROW);
    const int r = l >> 1, hb = l & 1;
    {
        int nr = nb + r; if (nr >= NN) nr = NN - 1;
        const _Float16* src = g1h + (size_t)nr * 128 + hb * 64;
        _Float16* dst = g16 + r * GROW + hb * 64;
#pragma unroll
        for (int q = 0; q < 8; q++)
            *(f16x8*)(dst + q * 8) = *(const f16x8*)(src + q * 8);
    }
    f16x8 bf[8];
#pragma unroll
    for (int ks = 0; ks < 8; ks++)
        bf[ks] = *(const f16x8*)(g16 + col * GROW + ks * 16 + hf * 8);
    f32x16 acc0, acc1;
#pragma unroll
    for (int i = 0; i < 16; i++) { acc0[i] = 0.f; acc1[i] = 0.f; }
#pragma unroll
    for (int ks = 0; ks < 8; ks++) {
        f16x8 a0 = *(const f16x8*)(apw2 + ((0 * 8 + ks) * 64 + l) * 8);
        f16x8 a1 = *(const f16x8*)(apw2 + ((1 * 8 + ks) * 64 + l) * 8);
        acc0 = __builtin_amdgcn_mfma_f32_32x32x16_f16(a0, bf[ks], acc0, 0, 0, 0);
        acc1 = __builtin_amdgcn_mfma_f32_32x32x16_f16(a1, bf[ks], acc1, 0, 0, 0);
    }
    _Float16* c16 = g16;
#pragma unroll
    for (int rg = 0; rg < 4; rg++) {
        f16x4 h0, h1;
#pragma unroll
        for (int i = 0; i < 4; i++) { h0[i] = (_Float16)acc0[rg * 4 + i]; h1[i] = (_Float16)acc1[rg * 4 + i]; }
        *(f16x4*)(c16 + col * CROW + rg * 8 + hf * 4) = h0;
        *(f16x4*)(c16 + col * CROW + 32 + rg * 8 + hf * 4) = h1;
    }
    if (nb + r < NN) {
        _Float16* dst = h2h + (size_t)(nb + r) * 64 + hb * 32;
        const _Float16* srow = c16 + r * CROW + hb * 32;
#pragma unroll
        for (int q = 0; q < 4; q++)
            *(f16x8*)(dst + q * 8) = *(const f16x8*)(srow + q * 8);
    }
}

// ---------- fused attention: writes packed fp16 A-fragments directly + fused bias ----------
__global__ void k_fuse(const float* __restrict__ enc_in_w, const float* __restrict__ enc_in_b,
                       const float* __restrict__ enc_out_w, const float* __restrict__ enc_out_b,
                       const float* __restrict__ sa_in_w, const float* __restrict__ sa_in_b,
                       const float* __restrict__ sa_out_w, const float* __restrict__ sa_out_b,
                       const float* __restrict__ ca_in_w, const float* __restrict__ ca_in_b,
                       const float* __restrict__ ca_out_w, const float* __restrict__ ca_out_b,
                       _Float16* __restrict__ apk, float* __restrict__ fb) {
    int tid = blockIdx.x * 256 + threadIdx.x;  // 6*64*64 = 24576 exact
    int p = tid >> 12, r = tid & 4095, j = r >> 6, k = r & 63;
    int li = p & 1;
    const float *iw, *ib, *ow, *ob;
    if (p < 2)      { iw = enc_in_w + li * 12288; ib = enc_in_b + li * 192; ow = enc_out_w + li * 4096; ob = enc_out_b + li * 64; }
    else if (p < 4) { iw = sa_in_w + li * 12288;  ib = sa_in_b + li * 192;  ow = sa_out_w + li * 4096;  ob = sa_out_b + li * 64; }
    else            { iw = ca_in_w + li * 12288;  ib = ca_in_b + li * 192;  ow = ca_out_w + li * 4096;  ob = ca_out_b + li * 64; }
    float a = 0.f;
    for (int m = 0; m < 64; m++) a = fmaf(ow[j * 64 + m], iw[(128 + m) * 64 + k], a);
    int l = ((k >> 3) & 1) * 32 + (j & 31);
    apk[p * 4096 + (((j >> 5) * 4 + (k >> 4)) * 64 + l) * 8 + (k & 7)] = (_Float16)a;
    if (k == 0) {
        float fa = ob[j];
        for (int m = 0; m < 64; m++) fa = fmaf(ow[j * 64 + m], ib[128 + m], fa);
        fb[p * 64 + j] = fa;
    }
}

// ---------- pack FFN weights (direct from inputs) + gat2_w A-fragments ----------
#define APK_F1 24576
#define APK_F2 90112
#define APK_TOT 155648
__global__ void k_apack(const float* __restrict__ ef1, const float* __restrict__ df1,
                        const float* __restrict__ ef2, const float* __restrict__ df2,
                        const float* __restrict__ g2w, _Float16* __restrict__ apk,
                        _Float16* __restrict__ apw2) {
    int tid = blockIdx.x * 256 + threadIdx.x;  // 544*256 = 139264 exact
    if (tid < 65536) {
        int pl = tid >> 14, idx = tid & 16383;
        int mt = idx >> 11, ks = (idx >> 9) & 3, l = (idx >> 3) & 63, d = idx & 7;
        int m = mt * 32 + (l & 31), k = ks * 16 + (l >> 5) * 8 + d;
        const float* f1 = (pl < 2) ? ef1 + pl * 16384 : df1 + (pl - 2) * 16384;
        apk[APK_F1 + pl * 16384 + idx] = (_Float16)f1[m * 64 + k];
    } else if (tid < 131072) {
        int r = tid - 65536;
        int pl = r >> 14, idx = r & 16383;
        int mt = idx >> 13, ks = (idx >> 9) & 15, l = (idx >> 3) & 63, d = idx & 7;
        int m = mt * 32 + (l & 31), k = ks * 16 + (l >> 5) * 8 + d;
        const float* f2 = (pl < 2) ? ef2 + pl * 16384 : df2 + (pl - 2) * 16384;
        apk[APK_F2 + pl * 16384 + idx] = (_Float16)f2[m * 256 + k];
    } else {
        int r = tid - 131072;
        int mtks = r >> 9, l = (r >> 3) & 63, d = r & 7;
        int mt = mtks >> 3, ks = mtks & 7;
        int m = mt * 32 + (l & 31), k = ks * 16 + (l >> 5) * 8 + d;
        apw2[r] = (_Float16)g2w[m * 128 + k];
    }
}

// ---------- MFMA transformer: 1 wave = 64 nodes + block-shared LDS weight staging ----------
// All 4 waves read identical A-fragments -> stage each stage's fragments into a
// shared 16KB LDS buffer once per block (cooperative copy), read via conflict-free
// ds_read_b128 (lane l reads bytes [l*16, l*16+16)). 4x less global weight traffic
// and ~12-cyc LDS reads replace ~200-cyc L2 loads in the dependent chain.
struct XQ {
    const _Float16* apk; const float* fb;
    const float* ef1b; const float* ef2b; const float* df1b; const float* df2b;
    const float* el1g; const float* el1b; const float* el2g; const float* el2b;
    const float* dl1g; const float* dl1b; const float* dl2g; const float* dl2b;
    const float* dl3g; const float* dl3b;
};

__device__ __forceinline__ void xstore(_Float16* xw, const float y[4][16], int col, int hf) {
#pragma unroll
    for (int nt = 0; nt < 2; nt++)
#pragma unroll
        for (int mt = 0; mt < 2; mt++)
#pragma unroll
            for (int rg = 0; rg < 4; rg++) {
                f16x4 h4;
#pragma unroll
                for (int i = 0; i < 4; i++) h4[i] = (_Float16)y[mt * 2 + nt][rg * 4 + i];
                *(f16x4*)(xw + (nt * 32 + col) * XROW + mt * 32 + rg * 8 + hf * 4) = h4;
            }
}

__device__ __forceinline__ void loadbf(const _Float16* xw, f16x8 bf[2][4], int col, int hf) {
#pragma unroll
    for (int nt = 0; nt < 2; nt++)
#pragma unroll
        for (int ks = 0; ks < 4; ks++)
            bf[nt][ks] = *(const f16x8*)(xw + (nt * 32 + col) * XROW + ks * 16 + hf * 8);
}

__device__ __forceinline__ void lnw(float y[4][16], const float* g, const float* b, int hf) {
#pragma unroll
    for (int nt = 0; nt < 2; nt++) {
        float s = 0.f, q = 0.f;
#pragma unroll
        for (int mt = 0; mt < 2; mt++)
#pragma unroll
            for (int r = 0; r < 16; r++) { float v = y[mt * 2 + nt][r]; s += v; q = fmaf(v, v, q); }
        s += __shfl_xor(s, 32, 64);
        q += __shfl_xor(q, 32, 64);
        float m = s * 0.015625f;
        float var = fmaf(q, 0.015625f, -m * m);
        float rs = rsqrtf(var + 1e-5f);
#pragma unroll
        for (int mt = 0; mt < 2; mt++)
#pragma unroll
            for (int rg = 0; rg < 4; rg++) {
                float4 g4 = *(const float4*)(g + mt * 32 + rg * 8 + hf * 4);
                float4 b4 = *(const float4*)(b + mt * 32 + rg * 8 + hf * 4);
                float* yp = &y[mt * 2 + nt][rg * 4];
                yp[0] = fmaf((yp[0] - m) * rs, g4.x, b4.x);
                yp[1] = fmaf((yp[1] - m) * rs, g4.y, b4.y);
                yp[2] = fmaf((yp[2] - m) * rs, g4.z, b4.z);
                yp[3] = fmaf((yp[3] - m) * rs, g4.w, b4.w);
            }
    }
}

__global__ __launch_bounds__(256, 2) void k_xform(const _Float16* __restrict__ yin,
                                                  float* __restrict__ yout, XQ P) {
    __shared__ _Float16 xs[4 * 64 * XROW];  // per-wave y/h transpose buffers
    __shared__ _Float16 wb[8192];           // shared weight stage: [0,4096)=attn/F1, [4096,8192)=F2
    const int t = threadIdx.x;
    const int w = t >> 6, l = t & 63;
    const int col = l & 31, hf = l >> 5;
    _Float16* xw = xs + w * (64 * XROW);
    const int nb = blockIdx.x * 256 + w * 64;
    const int nn0 = nb + col, nn1 = nb + 32 + col;
    const int nc0 = nn0 < NN ? nn0 : NN - 1;
    const int nc1 = nn1 < NN ? nn1 : NN - 1;

    float y[4][16];
#pragma unroll
    for (int mt = 0; mt < 2; mt++)
#pragma unroll
        for (int nt = 0; nt < 2; nt++) {
            const _Float16* src = yin + (size_t)(nt ? nc1 : nc0) * 64 + mt * 32 + hf * 4;
#pragma unroll
            for (int rg = 0; rg < 4; rg++) {
                f16x4 v = *(const f16x4*)(src + rg * 8);
#pragma unroll
                for (int i = 0; i < 4; i++) y[mt * 2 + nt][rg * 4 + i] = (float)v[i];
            }
        }
    f16x8 bf[2][4];
    xstore(xw, y, col, hf);
    loadbf(xw, bf, col, hf);

#pragma unroll 1
    for (int layer = 0; layer < 4; layer++) {
        const bool enc = layer < 2;
        const int li = enc ? layer : layer - 2;
        const int nat = enc ? 1 : 2;
#pragma unroll 1
        for (int at = 0; at < nat; at++) {
            const int p = enc ? layer : (at == 0 ? 2 + li : 4 + li);
            const _Float16* apA = P.apk + p * 4096;
            __syncthreads();  // prior wb readers done
#pragma unroll
            for (int i = 0; i < 2; i++)
                *(f16x8*)(wb + (t + i * 256) * 8) = *(const f16x8*)(apA + (t + i * 256) * 8);
            __syncthreads();  // wb visible
            const float* fbp = P.fb + p * 64;
            f32x16 acc[4];
#pragma unroll
            for (int mt = 0; mt < 2; mt++) {
                f32x16 a;
#pragma unroll
                for (int rg = 0; rg < 4; rg++) {
                    float4 b4 = *(const float4*)(fbp + mt * 32 + rg * 8 + hf * 4);
                    a[rg * 4 + 0] = b4.x; a[rg * 4 + 1] = b4.y; a[rg * 4 + 2] = b4.z; a[rg * 4 + 3] = b4.w;
                }
                acc[mt * 2 + 0] = a; acc[mt * 2 + 1] = a;
            }
#pragma unroll
            for (int mt = 0; mt < 2; mt++)
#pragma unroll
                for (int ks = 0; ks < 4; ks++) {
                    f16x8 af = *(const f16x8*)(wb + ((mt * 4 + ks) * 64 + l) * 8);
                    acc[mt * 2 + 0] = __builtin_amdgcn_mfma_f32_32x32x16_f16(af, bf[0][ks], acc[mt * 2 + 0], 0, 0, 0);
                    acc[mt * 2 + 1] = __builtin_amdgcn_mfma_f32_32x32x16_f16(af, bf[1][ks], acc[mt * 2 + 1], 0, 0, 0);
                }
#pragma unroll
            for (int ti = 0; ti < 4; ti++)
#pragma unroll
                for (int r = 0; r < 16; r++) y[ti][r] += acc[ti][r];
            const float *g, *b;
            if (enc)          { g = P.el1g + li * 64; b = P.el1b + li * 64; }
            else if (at == 0) { g = P.dl1g + li * 64; b = P.dl1b + li * 64; }
            else              { g = P.dl2g + li * 64; b = P.dl2b + li * 64; }
            lnw(y, g, b, hf);
            xstore(xw, y, col, hf);
            loadbf(xw, bf, col, hf);
        }
        const int pl = enc ? layer : 2 + li;
        const _Float16* apF1 = P.apk + APK_F1 + pl * 16384;
        const _Float16* apF2 = P.apk + APK_F2 + pl * 16384;
        const float* f1bp = (enc ? P.ef1b : P.df1b) + li * 256;
        const float* f2bp = (enc ? P.ef2b : P.df2b) + li * 64;
        f32x16 out[4];
#pragma unroll
        for (int mt = 0; mt < 2; mt++) {
            f32x16 a;
#pragma unroll
            for (int rg = 0; rg < 4; rg++) {
                float4 b4 = *(const float4*)(f2bp + mt * 32 + rg * 8 + hf * 4);
                a[rg * 4 + 0] = b4.x; a[rg * 4 + 1] = b4.y; a[rg * 4 + 2] = b4.z; a[rg * 4 + 3] = b4.w;
            }
            out[mt * 2 + 0] = a; out[mt * 2 + 1] = a;
        }
#pragma unroll 1
        for (int c = 0; c < 4; c++) {
            __syncthreads();  // prior wb readers done
            // F1 chunk c: contiguous 4096 halves at apF1 + c*4096
#pragma unroll
            for (int i = 0; i < 2; i++)
                *(f16x8*)(wb + (t + i * 256) * 8) = *(const f16x8*)(apF1 + c * 4096 + (t + i * 256) * 8);
            // F2 chunk c: two contiguous 2048-half runs (mt=0,1)
            *(f16x8*)(wb + 4096 + t * 8) = *(const f16x8*)(apF2 + c * 2048 + t * 8);
            *(f16x8*)(wb + 6144 + t * 8) = *(const f16x8*)(apF2 + 8192 + c * 2048 + t * 8);
            __syncthreads();  // wb visible
            f32x16 ha[4];
#pragma unroll
            for (int hmt = 0; hmt < 2; hmt++) {
                f32x16 a;
#pragma unroll
                for (int rg = 0; rg < 4; rg++) {
                    float4 b4 = *(const float4*)(f1bp + c * 64 + hmt * 32 + rg * 8 + hf * 4);
                    a[rg * 4 + 0] = b4.x; a[rg * 4 + 1] = b4.y; a[rg * 4 + 2] = b4.z; a[rg * 4 + 3] = b4.w;
                }
                ha[hmt * 2 + 0] = a; ha[hmt * 2 + 1] = a;
            }
#pragma unroll
            for (int hmt = 0; hmt < 2; hmt++)
#pragma unroll
                for (int ks = 0; ks < 4; ks++) {
                    f16x8 af = *(const f16x8*)(wb + ((hmt * 4 + ks) * 64 + l) * 8);
                    ha[hmt * 2 + 0] = __builtin_amdgcn_mfma_f32_32x32x16_f16(af, bf[0][ks], ha[hmt * 2 + 0], 0, 0, 0);
                    ha[hmt * 2 + 1] = __builtin_amdgcn_mfma_f32_32x32x16_f16(af, bf[1][ks], ha[hmt * 2 + 1], 0, 0, 0);
                }
            // ReLU + transpose chunk through per-wave xs (bf regs keep y)
#pragma unroll
            for (int nt = 0; nt < 2; nt++)
#pragma unroll
                for (int hmt = 0; hmt < 2; hmt++)
#pragma unroll
                    for (int rg = 0; rg < 4; rg++) {
                        f16x4 h4;
#pragma unroll
                        for (int i = 0; i < 4; i++)
                            h4[i] = (_Float16)fmaxf(ha[hmt * 2 + nt][rg * 4 + i], 0.f);
                        *(f16x4*)(xw + (nt * 32 + col) * XROW + hmt * 32 + rg * 8 + hf * 4) = h4;
                    }
#pragma unroll
            for (int ksl = 0; ksl < 4; ksl++) {
                f16x8 hbf0 = *(const f16x8*)(xw + col * XROW + ksl * 16 + hf * 8);
                f16x8 hbf1 = *(const f16x8*)(xw + (32 + col) * XROW + ksl * 16 + hf * 8);
#pragma unroll
                for (int mt = 0; mt < 2; mt++) {
                    f16x8 af = *(const f16x8*)(wb + 4096 + mt * 2048 + (ksl * 64 + l) * 8);
                    out[mt * 2 + 0] = __builtin_amdgcn_mfma_f32_32x32x16_f16(af, hbf0, out[mt * 2 + 0], 0, 0, 0);
                    out[mt * 2 + 1] = __builtin_amdgcn_mfma_f32_32x32x16_f16(af, hbf1, out[mt * 2 + 1], 0, 0, 0);
                }
            }
        }
#pragma unroll
        for (int ti = 0; ti < 4; ti++)
#pragma unroll
            for (int r = 0; r < 16; r++) y[ti][r] += out[ti][r];
        const float* g2 = (enc ? P.el2g : P.dl3g) + li * 64;
        const float* b2 = (enc ? P.el2b : P.dl3b) + li * 64;
        lnw(y, g2, b2, hf);
        if (layer < 3) {
            xstore(xw, y, col, hf);
            loadbf(xw, bf, col, hf);
        }
    }
#pragma unroll
    for (int mt = 0; mt < 2; mt++)
#pragma unroll
        for (int nt = 0; nt < 2; nt++) {
            int n = nt ? nn1 : nn0;
            if (n < NN) {
                float* dst = yout + (size_t)n * 64 + mt * 32 + hf * 4;
#pragma unroll
                for (int rg = 0; rg < 4; rg++) {
                    const float* yp = &y[mt * 2 + nt][rg * 4];
                    *(float4*)(dst + rg * 8) = make_float4(yp[0], yp[1], yp[2], yp[3]);
                }
            }
        }
}

// ---------- global mean pool ----------
__global__ void k_pool(const float* __restrict__ y, const int* __restrict__ batch,
                       float* __restrict__ pooled) {
    int b = blockIdx.x;
    int t = threadIdx.x;
    int ch = t & 63, r = t >> 6;
    int lo = 0, hi = NN;
    while (lo < hi) { int mid = (lo + hi) >> 1; if (batch[mid] < b) lo = mid + 1; else hi = mid; }
    int st = lo;
    hi = NN;
    while (lo < hi) { int mid = (lo + hi) >> 1; if (batch[mid] < b + 1) lo = mid + 1; else hi = mid; }
    int en = lo;
    float s = 0.f;
    for (int i = st + r; i < en; i += 4) s += y[(size_t)i * 64 + ch];
    __shared__ float red[256];
    red[t] = s;
    __syncthreads();
    if (t < 64) {
        float tot = red[t] + red[t + 64] + red[t + 128] + red[t + 192];
        int cnt = en - st; if (cnt < 1) cnt = 1;
        pooled[b * 64 + t] = tot / (float)cnt;
    }
}

// ---------- final fc ----------
__global__ void k_fc(const float* __restrict__ pooled, const float* __restrict__ fcw,
                     const float* __restrict__ fcb, float* __restrict__ out) {
    int tid = blockIdx.x * 256 + threadIdx.x;
    if (tid >= NG * 33) return;
    int g = tid / 33, o = tid - g * 33;
    const float* p = pooled + g * 64;
    const float* w = fcw + o * 64;
    float a0 = 0.f, a1 = 0.f, a2 = 0.f, a3 = 0.f;
#pragma unroll
    for (int k = 0; k < 16; k++) {
        a0 = fmaf(p[4 * k], w[4 * k], a0);
        a1 = fmaf(p[4 * k + 1], w[4 * k + 1], a1);
        a2 = fmaf(p[4 * k + 2], w[4 * k + 2], a2);
        a3 = fmaf(p[4 * k + 3], w[4 * k + 3], a3);
    }
    out[tid] = fcb[o] + (a0 + a1) + (a2 + a3);
}

extern "C" void kernel_launch(void* const* d_in, const int* in_sizes, int n_in,
                              void* d_out, int out_size, void* d_ws, size_t ws_size,
                              hipStream_t stream) {
    (void)in_sizes; (void)n_in; (void)out_size; (void)ws_size;
    char* ws = (char*)d_ws;
    size_t o = 0;
    auto A = [&](size_t b) { size_t r = o; o += (b + 255) & ~(size_t)255; return r; };
    _Float16* h1p = (_Float16*)(ws + A((size_t)NN * 128 * 2));
    _Float16* h2h = (_Float16*)(ws + A((size_t)NN * 64 * 2));
    _Float16* g1h = (_Float16*)(ws + A((size_t)NN * 128 * 2));
    _Float16* g2h = (_Float16*)(ws + A((size_t)NN * 64 * 2));
    float* f_y   = (float*)(ws + A((size_t)NN * 64 * 4));
    float* f_asp = (float*)(ws + A((size_t)NN * 4 * 4));
    float* f_ad1 = (float*)(ws + A((size_t)NN * 4 * 4));
    float* f_as2 = (float*)(ws + A((size_t)NN * 4 * 4));
    float* f_ad2 = (float*)(ws + A((size_t)NN * 4 * 4));
    int* i_off   = (int*)(ws + A((size_t)(NN + 1) * 4));
    int* i_cur   = (int*)(ws + A((size_t)NN * 4));
    int* i_deg   = (int*)(ws + A((size_t)NN * 4));
    int* i_bsum  = (int*)(ws + A((size_t)1024 * 4));
    int* i_srcs  = (int*)(ws + A((size_t)ETOT * 4));
    float* f_fb  = (float*)(ws + A((size_t)6 * 64 * 4));
    _Float16* f_apk = (_Float16*)(ws + A((size_t)APK_TOT * 2));
    _Float16* apw2  = (_Float16*)(ws + A((size_t)8192 * 2));
    float* f_pool= (float*)(ws + A((size_t)NG * 64 * 4));

    const float* x   = (const float*)d_in[0];
    const int* ei    = (const int*)d_in[1];
    const int* batch = (const int*)d_in[2];
    #define F32(i) ((const float*)d_in[i])

    hipMemsetAsync(i_deg, 0, (size_t)NN * 4, stream);
    k_h1<<<NN * 64 / 256, 256, 0, stream>>>(x, F32(3), F32(4), F32(5), F32(6), F32(7),
                                            h1p, f_asp, f_ad1);
    k_count<<<8 * 128, 256, 0, stream>>>(ei, i_deg);
    k_scan1<<<98, 1024, 0, stream>>>(i_deg, i_off, i_bsum);
    k_scan2<<<1, 128, 0, stream>>>(i_bsum);
    k_scan3<<<98, 1024, 0, stream>>>(i_off, i_bsum, i_cur);
    k_scatter<<<8 * 128, 256, 0, stream>>>(ei, i_cur, i_srcs);
    k_gat1<<<NN * 64 / 256, 256, 0, stream>>>(i_off, i_srcs, f_asp, f_ad1, h1p, F32(8), g1h);
    k_apack<<<544, 256, 0, stream>>>(F32(17), F32(33), F32(19), F32(35), F32(9), f_apk, apw2);
    k_h2m<<<(NN / 32 + 3) / 4, 256, 0, stream>>>(g1h, apw2, h2h);
    k_att2<<<(NN * 4 + 255) / 256, 256, 0, stream>>>(h2h, F32(10), F32(11), f_as2, f_ad2);
    k_gat2<<<NN * 64 / 256, 256, 0, stream>>>(i_off, i_srcs, f_as2, f_ad2, h2h, F32(12), g2h);
    k_fuse<<<24576 / 256, 256, 0, stream>>>(F32(13), F32(14), F32(15), F32(16),
                                            F32(25), F32(26), F32(27), F32(28),
                                            F32(29), F32(30), F32(31), F32(32),
                                            f_apk, f_fb);
    XQ Q;
    Q.apk = f_apk; Q.fb = f_fb;
    Q.ef1b = F32(18); Q.ef2b = F32(20);
    Q.df1b = F32(34); Q.df2b = F32(36);
    Q.el1g = F32(21); Q.el1b = F32(22); Q.el2g = F32(23); Q.el2b = F32(24);
    Q.dl1g = F32(37); Q.dl1b = F32(38); Q.dl2g = F32(39); Q.dl2b = F32(40);
    Q.dl3g = F32(41); Q.dl3b = F32(42);
    k_xform<<<(NN + 255) / 256, 256, 0, stream>>>(g2h, f_y, Q);
    k_pool<<<NG, 256, 0, stream>>>(f_y, batch, f_pool);
    k_fc<<<(NG * 33 + 255) / 256, 256, 0, stream>>>(f_pool, F32(43), F32(44), (float*)d_out);
    #undef F32
}

// Round 12
// 600.852 us; speedup vs baseline: 1.0865x; 1.0074x over previous
//
#include <hip/hip_runtime.h>

#define NN 100000
#define NE 1600000
#define NG 1000
#define ETOT (NE + NN)
#define NODES_PER_GRP 12500  // NN/8, XCD-affine binning for count/scatter

typedef _Float16 f16x8 __attribute__((ext_vector_type(8)));
typedef _Float16 f16x4 __attribute__((ext_vector_type(4)));
typedef _Float16 f16x2 __attribute__((ext_vector_type(2)));
typedef float f32x16 __attribute__((ext_vector_type(16)));
#define XROW 72  // xform LDS row stride (halves)

// ---------- h1 paired fp16 + fused att1 (one wave per node) ----------
__global__ void k_h1(const float* __restrict__ x, const float* __restrict__ ffw,
                     const float* __restrict__ ffb, const float* __restrict__ g1w,
                     const float* __restrict__ asw, const float* __restrict__ adw,
                     _Float16* __restrict__ h1p, float* __restrict__ asp,
                     float* __restrict__ ad_) {
    int tid = blockIdx.x * 256 + threadIdx.x;  // NN*64 exact
    int n = __builtin_amdgcn_readfirstlane(tid >> 6);
    int jp = threadIdx.x & 63;
    float xv[4];
#pragma unroll
    for (int k = 0; k < 4; k++) xv[k] = x[n * 4 + k];
    float h0[8];
#pragma unroll
    for (int o = 0; o < 8; o++) {
        float a = ffb[o];
#pragma unroll
        for (int k = 0; k < 4; k++) a = fmaf(xv[k], ffw[o * 4 + k], a);
        h0[o] = a;
    }
    const float* w0 = g1w + jp * 8;
    const float* w1 = g1w + (jp + 64) * 8;
    float a0 = 0.f, a1 = 0.f;
#pragma unroll
    for (int k = 0; k < 8; k++) { a0 = fmaf(h0[k], w0[k], a0); a1 = fmaf(h0[k], w1[k], a1); }
    f16x2 r; r[0] = (_Float16)a0; r[1] = (_Float16)a1;
    *(f16x2*)(h1p + ((size_t)n * 64 + jp) * 2) = r;
    float p0 = a0 * asw[jp], p1 = a1 * asw[jp + 64];
    float d0 = a0 * adw[jp], d1 = a1 * adw[jp + 64];
#pragma unroll
    for (int m = 1; m <= 16; m <<= 1) {
        p0 += __shfl_xor(p0, m, 64); p1 += __shfl_xor(p1, m, 64);
        d0 += __shfl_xor(d0, m, 64); d1 += __shfl_xor(d1, m, 64);
    }
    if ((jp & 31) == 0) {
        int half = jp >> 5;
        *(float2*)(asp + n * 4 + half * 2) = make_float2(p0, p1);
        ad_[n * 4 + half] = d0;
        ad_[n * 4 + 2 + half] = d1;
    }
}

// ---------- layer-2 attention coeffs ----------
__global__ void k_att2(const _Float16* __restrict__ h2h, const float* __restrict__ asw,
                       const float* __restrict__ adw, float* __restrict__ as_,
                       float* __restrict__ ad_) {
    int tid = blockIdx.x * 256 + threadIdx.x;
    if (tid >= NN * 4) return;
    int n = tid >> 2, h = tid & 3;
    const _Float16* hp = h2h + (size_t)n * 64 + h * 16;
    const float* ws_ = asw + h * 16;
    const float* wd_ = adw + h * 16;
    float a = 0.f, d = 0.f;
#pragma unroll
    for (int c = 0; c < 16; c++) {
        float hv = (float)hp[c];
        a = fmaf(hv, ws_[c], a); d = fmaf(hv, wd_[c], d);
    }
    as_[tid] = a; ad_[tid] = d;
}

// ---------- CSR build: XCD-affine binned count & scatter ----------
__global__ void k_count(const int* __restrict__ ei, int* __restrict__ deg) {
    int g = blockIdx.x & 7;
    int bi = blockIdx.x >> 3;
    int nb = gridDim.x >> 3;
    int lo = g * NODES_PER_GRP, hi = lo + NODES_PER_GRP;
    for (int e = bi * 256 + threadIdx.x; e < ETOT; e += nb * 256) {
        int dst = (e < NE) ? ei[NE + e] : (e - NE);
        if (dst >= lo && dst < hi) atomicAdd(&deg[dst], 1);
    }
}

__global__ void k_scan1(const int* __restrict__ deg, int* __restrict__ offs, int* __restrict__ bsum) {
    __shared__ int s[1024];
    int tid = threadIdx.x;
    int i = blockIdx.x * 1024 + tid;
    int v = (i < NN) ? deg[i] : 0;
    s[tid] = v;
    __syncthreads();
    for (int d = 1; d < 1024; d <<= 1) {
        int t = 0;
        if (tid >= d) t = s[tid - d];
        __syncthreads();
        if (tid >= d) s[tid] += t;
        __syncthreads();
    }
    if (i < NN) offs[i] = s[tid] - v;
    if (tid == 1023) bsum[blockIdx.x] = s[tid];
}

__global__ void k_scan2(int* __restrict__ bsum) {
    __shared__ int s[128];
    int tid = threadIdx.x;
    int v = (tid < 98) ? bsum[tid] : 0;
    s[tid] = v;
    __syncthreads();
    for (int d = 1; d < 128; d <<= 1) {
        int t = 0;
        if (tid >= d) t = s[tid - d];
        __syncthreads();
        if (tid >= d) s[tid] += t;
        __syncthreads();
    }
    bsum[tid] = s[tid] - v;
}

__global__ void k_scan3(int* __restrict__ offs, const int* __restrict__ bsum, int* __restrict__ cur) {
    int i = blockIdx.x * 1024 + threadIdx.x;
    if (i < NN) {
        int v = offs[i] + bsum[blockIdx.x];
        offs[i] = v; cur[i] = v;
    }
    if (i == 0) offs[NN] = ETOT;
}

__global__ void k_scatter(const int* __restrict__ ei, int* __restrict__ cur,
                          int* __restrict__ srcs, int* __restrict__ dsts) {
    int g = blockIdx.x & 7;
    int bi = blockIdx.x >> 3;
    int nb = gridDim.x >> 3;
    int lo = g * NODES_PER_GRP, hi = lo + NODES_PER_GRP;
    for (int e = bi * 256 + threadIdx.x; e < ETOT; e += nb * 256) {
        int dst = (e < NE) ? ei[NE + e] : (e - NE);
        if (dst >= lo && dst < hi) {
            int src = (e < NE) ? ei[e] : dst;
            int p = atomicAdd(&cur[dst], 1);
            srcs[p] = src;
            dsts[p] = dst;
        }
    }
}

// ---------- per-edge softmax weights, layer 1 ----------
// asp packed {as_h0, as_h2, as_h1, as_h3}; ad natural. ew[p] = {pack(w0,w2), pack(w1,w3)}
__global__ void k_ew1(const int* __restrict__ srcs, const int* __restrict__ dsts,
                      const float* __restrict__ asp, const float* __restrict__ ad_,
                      uint2* __restrict__ ew) {
    int p = blockIdx.x * 256 + threadIdx.x;
    if (p >= ETOT) return;
    int s = srcs[p], d = dsts[p];
    float4 a = *(const float4*)(asp + s * 4);   // {as0, as2, as1, as3}
    float4 b = *(const float4*)(ad_ + d * 4);   // {ad0, ad1, ad2, ad3}
    float e0 = a.x + b.x; e0 = fmaxf(e0, 0.2f * e0);
    float e2 = a.y + b.z; e2 = fmaxf(e2, 0.2f * e2);
    float e1 = a.z + b.y; e1 = fmaxf(e1, 0.2f * e1);
    float e3 = a.w + b.w; e3 = fmaxf(e3, 0.2f * e3);
    union { unsigned u; _Float16 h[2]; } c0, c1;
    c0.h[0] = (_Float16)__expf(e0); c0.h[1] = (_Float16)__expf(e2);
    c1.h[0] = (_Float16)__expf(e1); c1.h[1] = (_Float16)__expf(e3);
    uint2 o; o.x = c0.u; o.y = c1.u;
    ew[p] = o;
}

// ---------- per-edge softmax weights, layer 2 (natural head order) ----------
// ew[p] = {pack(w0,w1), pack(w2,w3)}
__global__ void k_ew2(const int* __restrict__ srcs, const int* __restrict__ dsts,
                      const float* __restrict__ as_, const float* __restrict__ ad_,
                      uint2* __restrict__ ew) {
    int p = blockIdx.x * 256 + threadIdx.x;
    if (p >= ETOT) return;
    int s = srcs[p], d = dsts[p];
    float4 a = *(const float4*)(as_ + s * 4);
    float4 b = *(const float4*)(ad_ + d * 4);
    float e0 = a.x + b.x; e0 = fmaxf(e0, 0.2f * e0);
    float e1 = a.y + b.y; e1 = fmaxf(e1, 0.2f * e1);
    float e2 = a.z + b.z; e2 = fmaxf(e2, 0.2f * e2);
    float e3 = a.w + b.w; e3 = fmaxf(e3, 0.2f * e3);
    union { unsigned u; _Float16 h[2]; } c0, c1;
    c0.h[0] = (_Float16)__expf(e0); c0.h[1] = (_Float16)__expf(e1);
    c1.h[0] = (_Float16)__expf(e2); c1.h[1] = (_Float16)__expf(e3);
    uint2 o; o.x = c0.u; o.y = c1.u;
    ew[p] = o;
}

// ---------- GAT layer 1: precomputed weights, scalar-load per edge ----------
__global__ void k_gat1(const int* __restrict__ offs, const int* __restrict__ srcs,
                       const uint2* __restrict__ ew, const _Float16* __restrict__ h1p,
                       const float* __restrict__ bias, _Float16* __restrict__ g1h) {
    int wid = __builtin_amdgcn_readfirstlane((blockIdx.x * 256 + threadIdx.x) >> 6);
    int lane = threadIdx.x & 63;
    if (wid >= NN) return;
    int off = offs[wid];
    int deg = offs[wid + 1] - off;
    int hA = lane >> 5;
    float ws0 = 0.f, ws1 = 0.f, ac0 = 0.f, ac1 = 0.f;
    float ws0b = 0.f, ws1b = 0.f, ac0b = 0.f, ac1b = 0.f;
    for (int base = 0; base < deg; base += 64) {
        int idx = off + base + lane; if (idx >= ETOT) idx = ETOT - 1;
        int sv = srcs[idx];
        int cnt = deg - base; if (cnt > 64) cnt = 64;
        int j = 0;
        for (; j + 2 <= cnt; j += 2) {
            int sa = __builtin_amdgcn_readlane(sv, j);
            int sb = __builtin_amdgcn_readlane(sv, j + 1);
            uint2 wva = ew[off + base + j];       // s_load_dwordx2 (scalar addr)
            uint2 wvb = ew[off + base + j + 1];
            f16x2 hpa = *(const f16x2*)(h1p + (size_t)sa * 128 + lane * 2);
            f16x2 hpb = *(const f16x2*)(h1p + (size_t)sb * 128 + lane * 2);
            union { unsigned u; _Float16 h[2]; } ca, cb;
            ca.u = hA ? wva.y : wva.x;
            cb.u = hA ? wvb.y : wvb.x;
            float w0 = (float)ca.h[0], w1 = (float)ca.h[1];
            float w0b = (float)cb.h[0], w1b = (float)cb.h[1];
            ws0 += w0; ws1 += w1;
            ac0 = fmaf(w0, (float)hpa[0], ac0); ac1 = fmaf(w1, (float)hpa[1], ac1);
            ws0b += w0b; ws1b += w1b;
            ac0b = fmaf(w0b, (float)hpb[0], ac0b); ac1b = fmaf(w1b, (float)hpb[1], ac1b);
        }
        if (j < cnt) {
            int sa = __builtin_amdgcn_readlane(sv, j);
            uint2 wva = ew[off + base + j];
            f16x2 hpa = *(const f16x2*)(h1p + (size_t)sa * 128 + lane * 2);
            union { unsigned u; _Float16 h[2]; } ca;
            ca.u = hA ? wva.y : wva.x;
            float w0 = (float)ca.h[0], w1 = (float)ca.h[1];
            ws0 += w0; ws1 += w1;
            ac0 = fmaf(w0, (float)hpa[0], ac0); ac1 = fmaf(w1, (float)hpa[1], ac1);
        }
    }
    ws0 += ws0b; ws1 += ws1b; ac0 += ac0b; ac1 += ac1b;
    float v0 = ac0 / ws0 + bias[lane];      v0 = fmaxf(v0, 0.01f * v0);
    float v1 = ac1 / ws1 + bias[lane + 64]; v1 = fmaxf(v1, 0.01f * v1);
    g1h[(size_t)wid * 128 + lane] = (_Float16)v0;
    g1h[(size_t)wid * 128 + lane + 64] = (_Float16)v1;
}

// ---------- GAT layer 2: precomputed weights ----------
__global__ void k_gat2(const int* __restrict__ offs, const int* __restrict__ srcs,
                       const uint2* __restrict__ ew, const _Float16* __restrict__ h2h,
                       const float* __restrict__ bias, _Float16* __restrict__ g2h) {
    int wid = __builtin_amdgcn_readfirstlane((blockIdx.x * 256 + threadIdx.x) >> 6);
    int lane = threadIdx.x & 63;
    if (wid >= NN) return;
    int off = offs[wid];
    int deg = offs[wid + 1] - off;
    int hd = lane >> 4;
    float ws = 0.f, ac = 0.f, wsb = 0.f, acb = 0.f;
    for (int base = 0; base < deg; base += 64) {
        int idx = off + base + lane; if (idx >= ETOT) idx = ETOT - 1;
        int sv = srcs[idx];
        int cnt = deg - base; if (cnt > 64) cnt = 64;
        int j = 0;
        for (; j + 2 <= cnt; j += 2) {
            int sa = __builtin_amdgcn_readlane(sv, j);
            int sb = __builtin_amdgcn_readlane(sv, j + 1);
            uint2 wva = ew[off + base + j];
            uint2 wvb = ew[off + base + j + 1];
            float ha = (float)h2h[(size_t)sa * 64 + lane];
            float hb = (float)h2h[(size_t)sb * 64 + lane];
            unsigned sela = (hd & 2) ? wva.y : wva.x;
            unsigned selb = (hd & 2) ? wvb.y : wvb.x;
            union { unsigned u; _Float16 h[2]; } ca, cb;
            ca.u = (hd & 1) ? (sela >> 16) : sela;
            cb.u = (hd & 1) ? (selb >> 16) : selb;
            float wa = (float)ca.h[0], wb = (float)cb.h[0];
            ws += wa; ac = fmaf(wa, ha, ac);
            wsb += wb; acb = fmaf(wb, hb, acb);
        }
        if (j < cnt) {
            int sa = __builtin_amdgcn_readlane(sv, j);
            uint2 wva = ew[off + base + j];
            unsigned sela = (hd & 2) ? wva.y : wva.x;
            union { unsigned u; _Float16 h[2]; } ca;
            ca.u = (hd & 1) ? (sela >> 16) : sela;
            float wa = (float)ca.h[0];
            ws += wa; ac = fmaf(wa, (float)h2h[(size_t)sa * 64 + lane], ac);
        }
    }
    ws += wsb; ac += acb;
    float v = ac / ws + bias[lane]; v = fmaxf(v, 0.01f * v);
    g2h[(size_t)wid * 64 + lane] = (_Float16)v;
}

// ---------- h2[N,64] fp16 = g1h[N,128] @ gat2_w.T via MFMA, 1 wave = 32 nodes ----------
#define GROW 136
#define CROW 72
__global__ __launch_bounds__(256, 2) void k_h2m(const _Float16* __restrict__ g1h,
                                                const _Float16* __restrict__ apw2,
                                                _Float16* __restrict__ h2h) {
    __shared__ _Float16 ls[4 * 32 * GROW];
    const int t = threadIdx.x;
    const int w = t >> 6, l = t & 63;
    const int col = l & 31, hf = l >> 5;
    const int wv = blockIdx.x * 4 + w;
    const int nb = wv * 32;
    if (nb >= NN) return;
    _Float16* g16 = ls + w * (32 * GROW);
    const int r = l >> 1, hb = l & 1;
    {
        int nr = nb + r; if (nr >= NN) nr = NN - 1;
        const _Float16* src = g1h + (size_t)nr * 128 + hb * 64;
        _Float16* dst = g16 + r * GROW + hb * 64;
#pragma unroll
        for (int q = 0; q < 8; q++)
            *(f16x8*)(dst + q * 8) = *(const f16x8*)(src + q * 8);
    }
    f16x8 bf[8];
#pragma unroll
    for (int ks = 0; ks < 8; ks++)
        bf[ks] = *(const f16x8*)(g16 + col * GROW + ks * 16 + hf * 8);
    f32x16 acc0, acc1;
#pragma unroll
    for (int i = 0; i < 16; i++) { acc0[i] = 0.f; acc1[i] = 0.f; }
#pragma unroll
    for (int ks = 0; ks < 8; ks++) {
        f16x8 a0 = *(const f16x8*)(apw2 + ((0 * 8 + ks) * 64 + l) * 8);
        f16x8 a1 = *(const f16x8*)(apw2 + ((1 * 8 + ks) * 64 + l) * 8);
        acc0 = __builtin_amdgcn_mfma_f32_32x32x16_f16(a0, bf[ks], acc0, 0, 0, 0);
        acc1 = __builtin_amdgcn_mfma_f32_32x32x16_f16(a1, bf[ks], acc1, 0, 0, 0);
    }
    _Float16* c16 = g16;
#pragma unroll
    for (int rg = 0; rg < 4; rg++) {
        f16x4 h0, h1;
#pragma unroll
        for (int i = 0; i < 4; i++) { h0[i] = (_Float16)acc0[rg * 4 + i]; h1[i] = (_Float16)acc1[rg * 4 + i]; }
        *(f16x4*)(c16 + col * CROW + rg * 8 + hf * 4) = h0;
        *(f16x4*)(c16 + col * CROW + 32 + rg * 8 + hf * 4) = h1;
    }
    if (nb + r < NN) {
        _Float16* dst = h2h + (size_t)(nb + r) * 64 + hb * 32;
        const _Float16* srow = c16 + r * CROW + hb * 32;
#pragma unroll
        for (int q = 0; q < 4; q++)
            *(f16x8*)(dst + q * 8) = *(const f16x8*)(srow + q * 8);
    }
}

// ---------- fused attention: writes packed fp16 A-fragments directly + fused bias ----------
__global__ void k_fuse(const float* __restrict__ enc_in_w, const float* __restrict__ enc_in_b,
                       const float* __restrict__ enc_out_w, const float* __restrict__ enc_out_b,
                       const float* __restrict__ sa_in_w, const float* __restrict__ sa_in_b,
                       const float* __restrict__ sa_out_w, const float* __restrict__ sa_out_b,
                       const float* __restrict__ ca_in_w, const float* __restrict__ ca_in_b,
                       const float* __restrict__ ca_out_w, const float* __restrict__ ca_out_b,
                       _Float16* __restrict__ apk, float* __restrict__ fb) {
    int tid = blockIdx.x * 256 + threadIdx.x;  // 6*64*64 = 24576 exact
    int p = tid >> 12, r = tid & 4095, j = r >> 6, k = r & 63;
    int li = p & 1;
    const float *iw, *ib, *ow, *ob;
    if (p < 2)      { iw = enc_in_w + li * 12288; ib = enc_in_b + li * 192; ow = enc_out_w + li * 4096; ob = enc_out_b + li * 64; }
    else if (p < 4) { iw = sa_in_w + li * 12288;  ib = sa_in_b + li * 192;  ow = sa_out_w + li * 4096;  ob = sa_out_b + li * 64; }
    else            { iw = ca_in_w + li * 12288;  ib = ca_in_b + li * 192;  ow = ca_out_w + li * 4096;  ob = ca_out_b + li * 64; }
    float a = 0.f;
    for (int m = 0; m < 64; m++) a = fmaf(ow[j * 64 + m], iw[(128 + m) * 64 + k], a);
    int l = ((k >> 3) & 1) * 32 + (j & 31);
    apk[p * 4096 + (((j >> 5) * 4 + (k >> 4)) * 64 + l) * 8 + (k & 7)] = (_Float16)a;
    if (k == 0) {
        float fa = ob[j];
        for (int m = 0; m < 64; m++) fa = fmaf(ow[j * 64 + m], ib[128 + m], fa);
        fb[p * 64 + j] = fa;
    }
}

// ---------- pack FFN weights (direct from inputs) + gat2_w A-fragments ----------
#define APK_F1 24576
#define APK_F2 90112
#define APK_TOT 155648
__global__ void k_apack(const float* __restrict__ ef1, const float* __restrict__ df1,
                        const float* __restrict__ ef2, const float* __restrict__ df2,
                        const float* __restrict__ g2w, _Float16* __restrict__ apk,
                        _Float16* __restrict__ apw2) {
    int tid = blockIdx.x * 256 + threadIdx.x;  // 544*256 = 139264 exact
    if (tid < 65536) {
        int pl = tid >> 14, idx = tid & 16383;
        int mt = idx >> 11, ks = (idx >> 9) & 3, l = (idx >> 3) & 63, d = idx & 7;
        int m = mt * 32 + (l & 31), k = ks * 16 + (l >> 5) * 8 + d;
        const float* f1 = (pl < 2) ? ef1 + pl * 16384 : df1 + (pl - 2) * 16384;
        apk[APK_F1 + pl * 16384 + idx] = (_Float16)f1[m * 64 + k];
    } else if (tid < 131072) {
        int r = tid - 65536;
        int pl = r >> 14, idx = r & 16383;
        int mt = idx >> 13, ks = (idx >> 9) & 15, l = (idx >> 3) & 63, d = idx & 7;
        int m = mt * 32 + (l & 31), k = ks * 16 + (l >> 5) * 8 + d;
        const float* f2 = (pl < 2) ? ef2 + pl * 16384 : df2 + (pl - 2) * 16384;
        apk[APK_F2 + pl * 16384 + idx] = (_Float16)f2[m * 256 + k];
    } else {
        int r = tid - 131072;
        int mtks = r >> 9, l = (r >> 3) & 63, d = r & 7;
        int mt = mtks >> 3, ks = mtks & 7;
        int m = mt * 32 + (l & 31), k = ks * 16 + (l >> 5) * 8 + d;
        apw2[r] = (_Float16)g2w[m * 128 + k];
    }
}

// ---------- MFMA transformer: 1 wave = 64 nodes + block-shared LDS weight staging ----------
struct XQ {
    const _Float16* apk; const float* fb;
    const float* ef1b; const float* ef2b; const float* df1b; const float* df2b;
    const float* el1g; const float* el1b; const float* el2g; const float* el2b;
    const float* dl1g; const float* dl1b; const float* dl2g; const float* dl2b;
    const float* dl3g; const float* dl3b;
};

__device__ __forceinline__ void xstore(_Float16* xw, const float y[4][16], int col, int hf) {
#pragma unroll
    for (int nt = 0; nt < 2; nt++)
#pragma unroll
        for (int mt = 0; mt < 2; mt++)
#pragma unroll
            for (int rg = 0; rg < 4; rg++) {
                f16x4 h4;
#pragma unroll
                for (int i = 0; i < 4; i++) h4[i] = (_Float16)y[mt * 2 + nt][rg * 4 + i];
                *(f16x4*)(xw + (nt * 32 + col) * XROW + mt * 32 + rg * 8 + hf * 4) = h4;
            }
}

__device__ __forceinline__ void loadbf(const _Float16* xw, f16x8 bf[2][4], int col, int hf) {
#pragma unroll
    for (int nt = 0; nt < 2; nt++)
#pragma unroll
        for (int ks = 0; ks < 4; ks++)
            bf[nt][ks] = *(const f16x8*)(xw + (nt * 32 + col) * XROW + ks * 16 + hf * 8);
}

__device__ __forceinline__ void lnw(float y[4][16], const float* g, const float* b, int hf) {
#pragma unroll
    for (int nt = 0; nt < 2; nt++) {
        float s = 0.f, q = 0.f;
#pragma unroll
        for (int mt = 0; mt < 2; mt++)
#pragma unroll
            for (int r = 0; r < 16; r++) { float v = y[mt * 2 + nt][r]; s += v; q = fmaf(v, v, q); }
        s += __shfl_xor(s, 32, 64);
        q += __shfl_xor(q, 32, 64);
        float m = s * 0.015625f;
        float var = fmaf(q, 0.015625f, -m * m);
        float rs = rsqrtf(var + 1e-5f);
#pragma unroll
        for (int mt = 0; mt < 2; mt++)
#pragma unroll
            for (int rg = 0; rg < 4; rg++) {
                float4 g4 = *(const float4*)(g + mt * 32 + rg * 8 + hf * 4);
                float4 b4 = *(const float4*)(b + mt * 32 + rg * 8 + hf * 4);
                float* yp = &y[mt * 2 + nt][rg * 4];
                yp[0] = fmaf((yp[0] - m) * rs, g4.x, b4.x);
                yp[1] = fmaf((yp[1] - m) * rs, g4.y, b4.y);
                yp[2] = fmaf((yp[2] - m) * rs, g4.z, b4.z);
                yp[3] = fmaf((yp[3] - m) * rs, g4.w, b4.w);
            }
    }
}

__global__ __launch_bounds__(256, 2) void k_xform(const _Float16* __restrict__ yin,
                                                  float* __restrict__ yout, XQ P) {
    __shared__ _Float16 xs[4 * 64 * XROW];
    __shared__ _Float16 wb[8192];
    const int t = threadIdx.x;
    const int w = t >> 6, l = t & 63;
    const int col = l & 31, hf = l >> 5;
    _Float16* xw = xs + w * (64 * XROW);
    const int nb = blockIdx.x * 256 + w * 64;
    const int nn0 = nb + col, nn1 = nb + 32 + col;
    const int nc0 = nn0 < NN ? nn0 : NN - 1;
    const int nc1 = nn1 < NN ? nn1 : NN - 1;

    float y[4][16];
#pragma unroll
    for (int mt = 0; mt < 2; mt++)
#pragma unroll
        for (int nt = 0; nt < 2; nt++) {
            const _Float16* src = yin + (size_t)(nt ? nc1 : nc0) * 64 + mt * 32 + hf * 4;
#pragma unroll
            for (int rg = 0; rg < 4; rg++) {
                f16x4 v = *(const f16x4*)(src + rg * 8);
#pragma unroll
                for (int i = 0; i < 4; i++) y[mt * 2 + nt][rg * 4 + i] = (float)v[i];
            }
        }
    f16x8 bf[2][4];
    xstore(xw, y, col, hf);
    loadbf(xw, bf, col, hf);

#pragma unroll 1
    for (int layer = 0; layer < 4; layer++) {
        const bool enc = layer < 2;
        const int li = enc ? layer : layer - 2;
        const int nat = enc ? 1 : 2;
#pragma unroll 1
        for (int at = 0; at < nat; at++) {
            const int p = enc ? layer : (at == 0 ? 2 + li : 4 + li);
            const _Float16* apA = P.apk + p * 4096;
            __syncthreads();
#pragma unroll
            for (int i = 0; i < 2; i++)
                *(f16x8*)(wb + (t + i * 256) * 8) = *(const f16x8*)(apA + (t + i * 256) * 8);
            __syncthreads();
            const float* fbp = P.fb + p * 64;
            f32x16 acc[4];
#pragma unroll
            for (int mt = 0; mt < 2; mt++) {
                f32x16 a;
#pragma unroll
                for (int rg = 0; rg < 4; rg++) {
                    float4 b4 = *(const float4*)(fbp + mt * 32 + rg * 8 + hf * 4);
                    a[rg * 4 + 0] = b4.x; a[rg * 4 + 1] = b4.y; a[rg * 4 + 2] = b4.z; a[rg * 4 + 3] = b4.w;
                }
                acc[mt * 2 + 0] = a; acc[mt * 2 + 1] = a;
            }
#pragma unroll
            for (int mt = 0; mt < 2; mt++)
#pragma unroll
                for (int ks = 0; ks < 4; ks++) {
                    f16x8 af = *(const f16x8*)(wb + ((mt * 4 + ks) * 64 + l) * 8);
                    acc[mt * 2 + 0] = __builtin_amdgcn_mfma_f32_32x32x16_f16(af, bf[0][ks], acc[mt * 2 + 0], 0, 0, 0);
                    acc[mt * 2 + 1] = __builtin_amdgcn_mfma_f32_32x32x16_f16(af, bf[1][ks], acc[mt * 2 + 1], 0, 0, 0);
                }
#pragma unroll
            for (int ti = 0; ti < 4; ti++)
#pragma unroll
                for (int r = 0; r < 16; r++) y[ti][r] += acc[ti][r];
            const float *g, *b;
            if (enc)          { g = P.el1g + li * 64; b = P.el1b + li * 64; }
            else if (at == 0) { g = P.dl1g + li * 64; b = P.dl1b + li * 64; }
            else              { g = P.dl2g + li * 64; b = P.dl2b + li * 64; }
            lnw(y, g, b, hf);
            xstore(xw, y, col, hf);
            loadbf(xw, bf, col, hf);
        }
        const int pl = enc ? layer : 2 + li;
        const _Float16* apF1 = P.apk + APK_F1 + pl * 16384;
        const _Float16* apF2 = P.apk + APK_F2 + pl * 16384;
        const float* f1bp = (enc ? P.ef1b : P.df1b) + li * 256;
        const float* f2bp = (enc ? P.ef2b : P.df2b) + li * 64;
        f32x16 out[4];
#pragma unroll
        for (int mt = 0; mt < 2; mt++) {
            f32x16 a;
#pragma unroll
            for (int rg = 0; rg < 4; rg++) {
                float4 b4 = *(const float4*)(f2bp + mt * 32 + rg * 8 + hf * 4);
                a[rg * 4 + 0] = b4.x; a[rg * 4 + 1] = b4.y; a[rg * 4 + 2] = b4.z; a[rg * 4 + 3] = b4.w;
            }
            out[mt * 2 + 0] = a; out[mt * 2 + 1] = a;
        }
#pragma unroll 1
        for (int c = 0; c < 4; c++) {
            __syncthreads();
#pragma unroll
            for (int i = 0; i < 2; i++)
                *(f16x8*)(wb + (t + i * 256) * 8) = *(const f16x8*)(apF1 + c * 4096 + (t + i * 256) * 8);
            *(f16x8*)(wb + 4096 + t * 8) = *(const f16x8*)(apF2 + c * 2048 + t * 8);
            *(f16x8*)(wb + 6144 + t * 8) = *(const f16x8*)(apF2 + 8192 + c * 2048 + t * 8);
            __syncthreads();
            f32x16 ha[4];
#pragma unroll
            for (int hmt = 0; hmt < 2; hmt++) {
                f32x16 a;
#pragma unroll
                for (int rg = 0; rg < 4; rg++) {
                    float4 b4 = *(const float4*)(f1bp + c * 64 + hmt * 32 + rg * 8 + hf * 4);
                    a[rg * 4 + 0] = b4.x; a[rg * 4 + 1] = b4.y; a[rg * 4 + 2] = b4.z; a[rg * 4 + 3] = b4.w;
                }
                ha[hmt * 2 + 0] = a; ha[hmt * 2 + 1] = a;
            }
#pragma unroll
            for (int hmt = 0; hmt < 2; hmt++)
#pragma unroll
                for (int ks = 0; ks < 4; ks++) {
                    f16x8 af = *(const f16x8*)(wb + ((hmt * 4 + ks) * 64 + l) * 8);
                    ha[hmt * 2 + 0] = __builtin_amdgcn_mfma_f32_32x32x16_f16(af, bf[0][ks], ha[hmt * 2 + 0], 0, 0, 0);
                    ha[hmt * 2 + 1] = __builtin_amdgcn_mfma_f32_32x32x16_f16(af, bf[1][ks], ha[hmt * 2 + 1], 0, 0, 0);
                }
#pragma unroll
            for (int nt = 0; nt < 2; nt++)
#pragma unroll
                for (int hmt = 0; hmt < 2; hmt++)
#pragma unroll
                    for (int rg = 0; rg < 4; rg++) {
                        f16x4 h4;
#pragma unroll
                        for (int i = 0; i < 4; i++)
                            h4[i] = (_Float16)fmaxf(ha[hmt * 2 + nt][rg * 4 + i], 0.f);
                        *(f16x4*)(xw + (nt * 32 + col) * XROW + hmt * 32 + rg * 8 + hf * 4) = h4;
                    }
#pragma unroll
            for (int ksl = 0; ksl < 4; ksl++) {
                f16x8 hbf0 = *(const f16x8*)(xw + col * XROW + ksl * 16 + hf * 8);
                f16x8 hbf1 = *(const f16x8*)(xw + (32 + col) * XROW + ksl * 16 + hf * 8);
#pragma unroll
                for (int mt = 0; mt < 2; mt++) {
                    f16x8 af = *(const f16x8*)(wb + 4096 + mt * 2048 + (ksl * 64 + l) * 8);
                    out[mt * 2 + 0] = __builtin_amdgcn_mfma_f32_32x32x16_f16(af, hbf0, out[mt * 2 + 0], 0, 0, 0);
                    out[mt * 2 + 1] = __builtin_amdgcn_mfma_f32_32x32x16_f16(af, hbf1, out[mt * 2 + 1], 0, 0, 0);
                }
            }
        }
#pragma unroll
        for (int ti = 0; ti < 4; ti++)
#pragma unroll
            for (int r = 0; r < 16; r++) y[ti][r] += out[ti][r];
        const float* g2 = (enc ? P.el2g : P.dl3g) + li * 64;
        const float* b2 = (enc ? P.el2b : P.dl3b) + li * 64;
        lnw(y, g2, b2, hf);
        if (layer < 3) {
            xstore(xw, y, col, hf);
            loadbf(xw, bf, col, hf);
        }
    }
#pragma unroll
    for (int mt = 0; mt < 2; mt++)
#pragma unroll
        for (int nt = 0; nt < 2; nt++) {
            int n = nt ? nn1 : nn0;
            if (n < NN) {
                float* dst = yout + (size_t)n * 64 + mt * 32 + hf * 4;
#pragma unroll
                for (int rg = 0; rg < 4; rg++) {
                    const float* yp = &y[mt * 2 + nt][rg * 4];
                    *(float4*)(dst + rg * 8) = make_float4(yp[0], yp[1], yp[2], yp[3]);
                }
            }
        }
}

// ---------- global mean pool ----------
__global__ void k_pool(const float* __restrict__ y, const int* __restrict__ batch,
                       float* __restrict__ pooled) {
    int b = blockIdx.x;
    int t = threadIdx.x;
    int ch = t & 63, r = t >> 6;
    int lo = 0, hi = NN;
    while (lo < hi) { int mid = (lo + hi) >> 1; if (batch[mid] < b) lo = mid + 1; else hi = mid; }
    int st = lo;
    hi = NN;
    while (lo < hi) { int mid = (lo + hi) >> 1; if (batch[mid] < b + 1) lo = mid + 1; else hi = mid; }
    int en = lo;
    float s = 0.f;
    for (int i = st + r; i < en; i += 4) s += y[(size_t)i * 64 + ch];
    __shared__ float red[256];
    red[t] = s;
    __syncthreads();
    if (t < 64) {
        float tot = red[t] + red[t + 64] + red[t + 128] + red[t + 192];
        int cnt = en - st; if (cnt < 1) cnt = 1;
        pooled[b * 64 + t] = tot / (float)cnt;
    }
}

// ---------- final fc ----------
__global__ void k_fc(const float* __restrict__ pooled, const float* __restrict__ fcw,
                     const float* __restrict__ fcb, float* __restrict__ out) {
    int tid = blockIdx.x * 256 + threadIdx.x;
    if (tid >= NG * 33) return;
    int g = tid / 33, o = tid - g * 33;
    const float* p = pooled + g * 64;
    const float* w = fcw + o * 64;
    float a0 = 0.f, a1 = 0.f, a2 = 0.f, a3 = 0.f;
#pragma unroll
    for (int k = 0; k < 16; k++) {
        a0 = fmaf(p[4 * k], w[4 * k], a0);
        a1 = fmaf(p[4 * k + 1], w[4 * k + 1], a1);
        a2 = fmaf(p[4 * k + 2], w[4 * k + 2], a2);
        a3 = fmaf(p[4 * k + 3], w[4 * k + 3], a3);
    }
    out[tid] = fcb[o] + (a0 + a1) + (a2 + a3);
}

extern "C" void kernel_launch(void* const* d_in, const int* in_sizes, int n_in,
                              void* d_out, int out_size, void* d_ws, size_t ws_size,
                              hipStream_t stream) {
    (void)in_sizes; (void)n_in; (void)out_size; (void)ws_size;
    char* ws = (char*)d_ws;
    size_t o = 0;
    auto A = [&](size_t b) { size_t r = o; o += (b + 255) & ~(size_t)255; return r; };
    _Float16* h1p = (_Float16*)(ws + A((size_t)NN * 128 * 2));
    _Float16* h2h = (_Float16*)(ws + A((size_t)NN * 64 * 2));
    _Float16* g1h = (_Float16*)(ws + A((size_t)NN * 128 * 2));
    _Float16* g2h = (_Float16*)(ws + A((size_t)NN * 64 * 2));
    float* f_y   = (float*)(ws + A((size_t)NN * 64 * 4));
    float* f_asp = (float*)(ws + A((size_t)NN * 4 * 4));
    float* f_ad1 = (float*)(ws + A((size_t)NN * 4 * 4));
    float* f_as2 = (float*)(ws + A((size_t)NN * 4 * 4));
    float* f_ad2 = (float*)(ws + A((size_t)NN * 4 * 4));
    int* i_off   = (int*)(ws + A((size_t)(NN + 1) * 4));
    int* i_cur   = (int*)(ws + A((size_t)NN * 4));
    int* i_deg   = (int*)(ws + A((size_t)NN * 4));
    int* i_bsum  = (int*)(ws + A((size_t)1024 * 4));
    int* i_srcs  = (int*)(ws + A((size_t)ETOT * 4));
    int* i_dsts  = (int*)(ws + A((size_t)ETOT * 4));
    uint2* e_w   = (uint2*)(ws + A((size_t)ETOT * 8));
    float* f_fb  = (float*)(ws + A((size_t)6 * 64 * 4));
    _Float16* f_apk = (_Float16*)(ws + A((size_t)APK_TOT * 2));
    _Float16* apw2  = (_Float16*)(ws + A((size_t)8192 * 2));
    float* f_pool= (float*)(ws + A((size_t)NG * 64 * 4));

    const float* x   = (const float*)d_in[0];
    const int* ei    = (const int*)d_in[1];
    const int* batch = (const int*)d_in[2];
    #define F32(i) ((const float*)d_in[i])

    hipMemsetAsync(i_deg, 0, (size_t)NN * 4, stream);
    k_h1<<<NN * 64 / 256, 256, 0, stream>>>(x, F32(3), F32(4), F32(5), F32(6), F32(7),
                                            h1p, f_asp, f_ad1);
    k_count<<<8 * 128, 256, 0, stream>>>(ei, i_deg);
    k_scan1<<<98, 1024, 0, stream>>>(i_deg, i_off, i_bsum);
    k_scan2<<<1, 128, 0, stream>>>(i_bsum);
    k_scan3<<<98, 1024, 0, stream>>>(i_off, i_bsum, i_cur);
    k_scatter<<<8 * 128, 256, 0, stream>>>(ei, i_cur, i_srcs, i_dsts);
    k_ew1<<<(ETOT + 255) / 256, 256, 0, stream>>>(i_srcs, i_dsts, f_asp, f_ad1, e_w);
    k_gat1<<<NN * 64 / 256, 256, 0, stream>>>(i_off, i_srcs, e_w, h1p, F32(8), g1h);
    k_apack<<<544, 256, 0, stream>>>(F32(17), F32(33), F32(19), F32(35), F32(9), f_apk, apw2);
    k_h2m<<<(NN / 32 + 3) / 4, 256, 0, stream>>>(g1h, apw2, h2h);
    k_att2<<<(NN * 4 + 255) / 256, 256, 0, stream>>>(h2h, F32(10), F32(11), f_as2, f_ad2);
    k_ew2<<<(ETOT + 255) / 256, 256, 0, stream>>>(i_srcs, i_dsts, f_as2, f_ad2, e_w);
    k_gat2<<<NN * 64 / 256, 256, 0, stream>>>(i_off, i_srcs, e_w, h2h, F32(12), g2h);
    k_fuse<<<24576 / 256, 256, 0, stream>>>(F32(13), F32(14), F32(15), F32(16),
                                            F32(25), F32(26), F32(27), F32(28),
                                            F32(29), F32(30), F32(31), F32(32),
                                            f_apk, f_fb);
    XQ Q;
    Q.apk = f_apk; Q.fb = f_fb;
    Q.ef1b = F32(18); Q.ef2b = F32(20);
    Q.df1b = F32(34); Q.df2b = F32(36);
    Q.el1g = F32(21); Q.el1b = F32(22); Q.el2g = F32(23); Q.el2b = F32(24);
    Q.dl1g = F32(37); Q.dl1b = F32(38); Q.dl2g = F32(39); Q.dl2b = F32(40);
    Q.dl3g = F32(41); Q.dl3b = F32(42);
    k_xform<<<(NN + 255) / 256, 256, 0, stream>>>(g2h, f_y, Q);
    k_pool<<<NG, 256, 0, stream>>>(f_y, batch, f_pool);
    k_fc<<<(NG * 33 + 255) / 256, 256, 0, stream>>>(f_pool, F32(43), F32(44), (float*)d_out);
    #undef F32
}